// Round 1
// baseline (553.168 us; speedup 1.0000x reference)
//
#include <hip/hip_runtime.h>
#include <hip/hip_bf16.h>

typedef __attribute__((ext_vector_type(8))) short bf16x8;
typedef __attribute__((ext_vector_type(4))) float f32x4;
typedef __attribute__((ext_vector_type(4))) unsigned short u16x4;
typedef unsigned short u16;

__device__ __forceinline__ u16 f2bf(float f) {
  unsigned u = __builtin_bit_cast(unsigned, f);
  u += 0x7fffu + ((u >> 16) & 1u);
  return (u16)(u >> 16);
}

__device__ __forceinline__ void gl_lds16(const void* g, void* l) {
  __builtin_amdgcn_global_load_lds((const __attribute__((address_space(1))) void*)g,
                                   (__attribute__((address_space(3))) void*)l,
                                   16, 0, 0);
}

// ---------------- f32 -> bf16 convert ----------------
__global__ __launch_bounds__(256) void cvt_f32_bf16(const float* __restrict__ in,
                                                    u16* __restrict__ out, int n4) {
  int i = blockIdx.x * 256 + threadIdx.x;
  const int stride = gridDim.x * 256;
  for (; i < n4; i += stride) {
    float4 v = ((const float4*)in)[i];
    u16x4 o;
    o.x = f2bf(v.x); o.y = f2bf(v.y); o.z = f2bf(v.z); o.w = f2bf(v.w);
    ((u16x4*)out)[i] = o;
  }
}

// ---------------- LayerNorm: f32 in, bf16 out (D=1024) ----------------
__global__ __launch_bounds__(256) void ln_k(const float* __restrict__ x,
                                            const float* __restrict__ g,
                                            const float* __restrict__ b,
                                            u16* __restrict__ out) {
  const int row = blockIdx.x;
  const int t = threadIdx.x;
  const int lane = t & 63, w = t >> 6;
  const float4 v = ((const float4*)(x + (size_t)row * 1024))[t];
  float s = v.x + v.y + v.z + v.w;
  float q = v.x * v.x + v.y * v.y + v.z * v.z + v.w * v.w;
#pragma unroll
  for (int off = 32; off; off >>= 1) {
    s += __shfl_down(s, off);
    q += __shfl_down(q, off);
  }
  __shared__ float red[8];
  if (lane == 0) { red[w] = s; red[4 + w] = q; }
  __syncthreads();
  s = red[0] + red[1] + red[2] + red[3];
  q = red[4] + red[5] + red[6] + red[7];
  const float mu = s * (1.f / 1024.f);
  const float var = q * (1.f / 1024.f) - mu * mu;
  const float rs = rsqrtf(var + 1e-5f);
  const float4 gv = ((const float4*)g)[t];
  const float4 bv = ((const float4*)b)[t];
  u16x4 o;
  o.x = f2bf((v.x - mu) * rs * gv.x + bv.x);
  o.y = f2bf((v.y - mu) * rs * gv.y + bv.y);
  o.z = f2bf((v.z - mu) * rs * gv.z + bv.z);
  o.w = f2bf((v.w - mu) * rs * gv.w + bv.w);
  ((u16x4*)(out + (size_t)row * 1024))[t] = o;
}

// ---------------- NT GEMM: C[M,N] = A[M,K] * B[N,K]^T (+bias, epilogue) ---
// EPI 0: bf16(v+bias)   1: f32 v+bias+res   2: bf16(relu(v+bias))
template <int EPI>
__global__ __launch_bounds__(256) void gemm_nt(const u16* __restrict__ A,
                                               const u16* __restrict__ B,
                                               const float* __restrict__ bias,
                                               const float* __restrict__ res,
                                               void* __restrict__ outp,
                                               int N, long K) {
  __shared__ u16 aLds[4096];
  __shared__ u16 bLds[4096];
  const int t = threadIdx.x;
  const int lane = t & 63, w = t >> 6;
  const int wm = w >> 1, wn = w & 1;
  const int l15 = lane & 15, lhi = lane >> 4;
  const long bm = (long)blockIdx.y * 128, bn = (long)blockIdx.x * 128;
  const int e0 = t * 8;
  const int r0 = e0 >> 5, c0 = e0 & 31;
  const u16* Ap = A + (bm + r0) * K + c0;
  const u16* Bp = B + (bn + r0) * K + c0;
  u16* aDst = &aLds[w * 512];
  u16* bDst = &bLds[w * 512];
  f32x4 acc[4][4] = {};
  for (long k0 = 0; k0 < K; k0 += 32) {
    gl_lds16(Ap + k0, aDst);
    gl_lds16(Ap + 64 * K + k0, aDst + 2048);
    gl_lds16(Bp + k0, bDst);
    gl_lds16(Bp + 64 * K + k0, bDst + 2048);
    __syncthreads();
    bf16x8 av[4], bv[4];
#pragma unroll
    for (int i = 0; i < 4; ++i)
      av[i] = *(const bf16x8*)&aLds[(wm * 64 + i * 16 + l15) * 32 + lhi * 8];
#pragma unroll
    for (int j = 0; j < 4; ++j)
      bv[j] = *(const bf16x8*)&bLds[(wn * 64 + j * 16 + l15) * 32 + lhi * 8];
#pragma unroll
    for (int i = 0; i < 4; ++i)
#pragma unroll
      for (int j = 0; j < 4; ++j)
        acc[i][j] = __builtin_amdgcn_mfma_f32_16x16x32_bf16(av[i], bv[j], acc[i][j], 0, 0, 0);
    __syncthreads();
  }
#pragma unroll
  for (int j = 0; j < 4; ++j) {
    const long col = bn + wn * 64 + j * 16 + l15;
    const float bj = bias[col];
#pragma unroll
    for (int i = 0; i < 4; ++i) {
      const long row0 = bm + wm * 64 + i * 16 + lhi * 4;
#pragma unroll
      for (int r = 0; r < 4; ++r) {
        const float v = acc[i][j][r] + bj;
        const long idx = (row0 + r) * N + col;
        if constexpr (EPI == 0) {
          ((u16*)outp)[idx] = f2bf(v);
        } else if constexpr (EPI == 1) {
          ((float*)outp)[idx] = v + res[idx];
        } else {
          ((u16*)outp)[idx] = f2bf(v > 0.f ? v : 0.f);
        }
      }
    }
  }
}

// ---------------- V transpose: qkv -> vt[bh][d][kv] ----------------
__global__ __launch_bounds__(256) void vtrans(const u16* __restrict__ qkv,
                                              u16* __restrict__ vt) {
  const int t = threadIdx.x;
  const int bh = blockIdx.y, b = bh >> 4, h = bh & 15;
  const int kvb = blockIdx.x * 64;
  __shared__ u16 tile[64][72];
  const u16* src = qkv + ((size_t)(b * 2048 + kvb)) * 3072 + h * 192 + 128;
#pragma unroll
  for (int rr = 0; rr < 2; ++rr) {
    const int e = rr * 2048 + t * 8;
    const int kv = e >> 6, d = e & 63;
    *(bf16x8*)&tile[kv][d] = *(const bf16x8*)(src + (size_t)kv * 3072 + d);
  }
  __syncthreads();
#pragma unroll
  for (int rr = 0; rr < 2; ++rr) {
    const int e = rr * 2048 + t * 8;
    const int d = e >> 6, kv = e & 63;
    bf16x8 o;
#pragma unroll
    for (int j = 0; j < 8; ++j) o[j] = (short)tile[kv + j][d];
    *(bf16x8*)(vt + ((size_t)bh * 64 + d) * 2048 + kvb + kv) = o;
  }
}

// ---------------- Flash attention ----------------
// grid (S/64, B*H), 4 waves, each wave owns 16 q rows; KV tiles of 64.
__global__ __launch_bounds__(256) void attn_k(const u16* __restrict__ qkv,
                                              const u16* __restrict__ vt,
                                              u16* __restrict__ ctx) {
  const int t = threadIdx.x;
  const int lane = t & 63, w = t >> 6;
  const int l15 = lane & 15, lhi = lane >> 4;
  const int bh = blockIdx.y, b = bh >> 4, h = bh & 15;
  const int q0 = blockIdx.x * 64 + w * 16;
  const u16* qp = qkv + ((size_t)(b * 2048 + q0 + l15)) * 3072 + h * 192 + lhi * 8;
  const bf16x8 qf0 = *(const bf16x8*)qp;
  const bf16x8 qf1 = *(const bf16x8*)(qp + 32);
  const u16* kb = qkv + (size_t)b * 2048 * 3072 + h * 192 + 64 + lhi * 8;
  const u16* vb = vt + (size_t)bh * 64 * 2048;
  __shared__ u16 plds[4][16][64];
  f32x4 o[4] = {};
  float m[4], lsum[4];
#pragma unroll
  for (int r = 0; r < 4; ++r) { m[r] = -1e30f; lsum[r] = 0.f; }
  for (int kv0 = 0; kv0 < 2048; kv0 += 64) {
    f32x4 s[4] = {};
#pragma unroll
    for (int jt = 0; jt < 4; ++jt) {
      const u16* kp = kb + (size_t)(kv0 + jt * 16 + l15) * 3072;
      s[jt] = __builtin_amdgcn_mfma_f32_16x16x32_bf16(qf0, *(const bf16x8*)kp, s[jt], 0, 0, 0);
      s[jt] = __builtin_amdgcn_mfma_f32_16x16x32_bf16(qf1, *(const bf16x8*)(kp + 32), s[jt], 0, 0, 0);
    }
#pragma unroll
    for (int r = 0; r < 4; ++r) {
      s[0][r] *= 0.125f; s[1][r] *= 0.125f; s[2][r] *= 0.125f; s[3][r] *= 0.125f;
      float mt = fmaxf(fmaxf(s[0][r], s[1][r]), fmaxf(s[2][r], s[3][r]));
      mt = fmaxf(mt, __shfl_xor(mt, 1));
      mt = fmaxf(mt, __shfl_xor(mt, 2));
      mt = fmaxf(mt, __shfl_xor(mt, 4));
      mt = fmaxf(mt, __shfl_xor(mt, 8));
      const float mn = fmaxf(m[r], mt);
      const float sc = __expf(m[r] - mn);
      m[r] = mn;
      float rsum = 0.f;
#pragma unroll
      for (int jt = 0; jt < 4; ++jt) {
        const float p = __expf(s[jt][r] - mn);
        s[jt][r] = p;
        rsum += p;
      }
      rsum += __shfl_xor(rsum, 1);
      rsum += __shfl_xor(rsum, 2);
      rsum += __shfl_xor(rsum, 4);
      rsum += __shfl_xor(rsum, 8);
      lsum[r] = lsum[r] * sc + rsum;
      o[0][r] *= sc; o[1][r] *= sc; o[2][r] *= sc; o[3][r] *= sc;
    }
#pragma unroll
    for (int jt = 0; jt < 4; ++jt)
#pragma unroll
      for (int r = 0; r < 4; ++r)
        plds[w][lhi * 4 + r][jt * 16 + l15] = f2bf(s[jt][r]);
    asm volatile("" ::: "memory");
#pragma unroll
    for (int ks = 0; ks < 2; ++ks) {
      const bf16x8 pf = *(const bf16x8*)&plds[w][l15][ks * 32 + lhi * 8];
      const u16* vp = vb + kv0 + ks * 32 + lhi * 8;
#pragma unroll
      for (int dt = 0; dt < 4; ++dt)
        o[dt] = __builtin_amdgcn_mfma_f32_16x16x32_bf16(
            pf, *(const bf16x8*)(vp + (size_t)(dt * 16 + l15) * 2048), o[dt], 0, 0, 0);
    }
    asm volatile("" ::: "memory");
  }
#pragma unroll
  for (int dt = 0; dt < 4; ++dt)
#pragma unroll
    for (int r = 0; r < 4; ++r) {
      const float v = o[dt][r] / lsum[r];
      const int sg = q0 + lhi * 4 + r;
      ctx[((size_t)b * 2048 + sg) * 1024 + h * 64 + dt * 16 + l15] = f2bf(v);
    }
}

extern "C" void kernel_launch(void* const* d_in, const int* in_sizes, int n_in,
                              void* d_out, int out_size, void* d_ws, size_t ws_size,
                              hipStream_t stream) {
  const float* x     = (const float*)d_in[0];
  const float* w_qkv = (const float*)d_in[1];
  const float* b_qkv = (const float*)d_in[2];
  const float* w_out = (const float*)d_in[3];
  const float* b_out = (const float*)d_in[4];
  const float* w1    = (const float*)d_in[5];
  const float* b1    = (const float*)d_in[6];
  const float* w2    = (const float*)d_in[7];
  const float* b2    = (const float*)d_in[8];
  const float* ln1g  = (const float*)d_in[9];
  const float* ln1b  = (const float*)d_in[10];
  const float* ln2g  = (const float*)d_in[11];
  const float* ln2b  = (const float*)d_in[12];
  float* out = (float*)d_out;

  u16* wqkv_b = (u16*)d_ws;                       // 3072*1024
  u16* wout_b = wqkv_b + (size_t)3072 * 1024;     // 1024*1024
  u16* w1_b   = wout_b + (size_t)1024 * 1024;     // 4096*1024
  u16* w2_b   = w1_b + (size_t)4096 * 1024;       // 1024*4096
  u16* r1     = w2_b + (size_t)1024 * 4096;       // 4096*1024: h1 / ctx / h2
  u16* r2     = r1 + (size_t)4096 * 1024;         // 4096*4096: qkv+vt, then hff
  u16* qkvb   = r2;
  u16* vtb    = r2 + (size_t)4096 * 3072;
  float* x2   = (float*)(r2 + (size_t)4096 * 4096); // 4096*1024 f32

  // weight conversion
  cvt_f32_bf16<<<1024, 256, 0, stream>>>(w_qkv, wqkv_b, 3072 * 1024 / 4);
  cvt_f32_bf16<<<1024, 256, 0, stream>>>(w_out, wout_b, 1024 * 1024 / 4);
  cvt_f32_bf16<<<1024, 256, 0, stream>>>(w1, w1_b, 4096 * 1024 / 4);
  cvt_f32_bf16<<<1024, 256, 0, stream>>>(w2, w2_b, 1024 * 4096 / 4);

  // LN1 -> h1 (r1)
  ln_k<<<4096, 256, 0, stream>>>(x, ln1g, ln1b, r1);
  // QKV GEMM: [4096,1024] x [3072,1024]^T -> qkv bf16
  gemm_nt<0><<<dim3(24, 32), 256, 0, stream>>>(r1, wqkv_b, b_qkv, nullptr, qkvb, 3072, 1024);
  // V transpose
  vtrans<<<dim3(32, 32), 256, 0, stream>>>(qkvb, vtb);
  // attention -> ctx (r1)
  attn_k<<<dim3(32, 32), 256, 0, stream>>>(qkvb, vtb, r1);
  // out-proj + residual -> x2 (f32)
  gemm_nt<1><<<dim3(8, 32), 256, 0, stream>>>(r1, wout_b, b_out, x, x2, 1024, 1024);
  // LN2 -> h2 (r1)
  ln_k<<<4096, 256, 0, stream>>>(x2, ln2g, ln2b, r1);
  // MLP1 + ReLU -> hff (r2)
  gemm_nt<2><<<dim3(32, 32), 256, 0, stream>>>(r1, w1_b, b1, nullptr, r2, 4096, 1024);
  // MLP2 + residual -> out (f32)
  gemm_nt<1><<<dim3(8, 32), 256, 0, stream>>>(r2, w2_b, b2, x2, out, 1024, 4096);
}

// Round 2
// 388.506 us; speedup vs baseline: 1.4238x; 1.4238x over previous
//
#include <hip/hip_runtime.h>
#include <hip/hip_bf16.h>

typedef __attribute__((ext_vector_type(8))) short bf16x8;
typedef __attribute__((ext_vector_type(4))) float f32x4;
typedef __attribute__((ext_vector_type(4))) unsigned short u16x4;
typedef unsigned short u16;

__device__ __forceinline__ u16 f2bf(float f) {
  unsigned u = __builtin_bit_cast(unsigned, f);
  u += 0x7fffu + ((u >> 16) & 1u);
  return (u16)(u >> 16);
}
__device__ __forceinline__ float bf2f(u16 u) {
  unsigned v = ((unsigned)u) << 16;
  return __builtin_bit_cast(float, v);
}

__device__ __forceinline__ void gl_lds16(const void* g, void* l) {
  __builtin_amdgcn_global_load_lds((const __attribute__((address_space(1))) void*)g,
                                   (__attribute__((address_space(3))) void*)l,
                                   16, 0, 0);
}

// ---------------- f32 -> bf16 convert ----------------
__global__ __launch_bounds__(256) void cvt_f32_bf16(const float* __restrict__ in,
                                                    u16* __restrict__ out, int n4) {
  int i = blockIdx.x * 256 + threadIdx.x;
  const int stride = gridDim.x * 256;
  for (; i < n4; i += stride) {
    float4 v = ((const float4*)in)[i];
    u16x4 o;
    o.x = f2bf(v.x); o.y = f2bf(v.y); o.z = f2bf(v.z); o.w = f2bf(v.w);
    ((u16x4*)out)[i] = o;
  }
}

// ---------------- LayerNorm: f32 in, bf16 out (D=1024) ----------------
__global__ __launch_bounds__(256) void ln_k(const float* __restrict__ x,
                                            const float* __restrict__ g,
                                            const float* __restrict__ b,
                                            u16* __restrict__ out) {
  const int row = blockIdx.x;
  const int t = threadIdx.x;
  const int lane = t & 63, w = t >> 6;
  const float4 v = ((const float4*)(x + (size_t)row * 1024))[t];
  float s = v.x + v.y + v.z + v.w;
  float q = v.x * v.x + v.y * v.y + v.z * v.z + v.w * v.w;
#pragma unroll
  for (int off = 32; off; off >>= 1) {
    s += __shfl_down(s, off);
    q += __shfl_down(q, off);
  }
  __shared__ float red[8];
  if (lane == 0) { red[w] = s; red[4 + w] = q; }
  __syncthreads();
  s = red[0] + red[1] + red[2] + red[3];
  q = red[4] + red[5] + red[6] + red[7];
  const float mu = s * (1.f / 1024.f);
  const float var = q * (1.f / 1024.f) - mu * mu;
  const float rs = rsqrtf(var + 1e-5f);
  const float4 gv = ((const float4*)g)[t];
  const float4 bv = ((const float4*)b)[t];
  u16x4 o;
  o.x = f2bf((v.x - mu) * rs * gv.x + bv.x);
  o.y = f2bf((v.y - mu) * rs * gv.y + bv.y);
  o.z = f2bf((v.z - mu) * rs * gv.z + bv.z);
  o.w = f2bf((v.w - mu) * rs * gv.w + bv.w);
  ((u16x4*)(out + (size_t)row * 1024))[t] = o;
}

// ---------------- NT GEMM: C[M,N] = A[M,K] * B[N,K]^T (+bias, epilogue) ---
// EPI 0: bf16(v+bias)   1: f32 v+bias+res   2: bf16(relu(v+bias))
template <int EPI>
__global__ __launch_bounds__(256) void gemm_nt(const u16* __restrict__ A,
                                               const u16* __restrict__ B,
                                               const float* __restrict__ bias,
                                               const float* __restrict__ res,
                                               void* __restrict__ outp,
                                               int N, long K) {
  __shared__ u16 aLds[4096];
  __shared__ u16 bLds[4096];
  const int t = threadIdx.x;
  const int lane = t & 63, w = t >> 6;
  const int wm = w >> 1, wn = w & 1;
  const int l15 = lane & 15, lhi = lane >> 4;
  const long bm = (long)blockIdx.y * 128, bn = (long)blockIdx.x * 128;
  const int e0 = t * 8;
  const int r0 = e0 >> 5, c0 = e0 & 31;
  const u16* Ap = A + (bm + r0) * K + c0;
  const u16* Bp = B + (bn + r0) * K + c0;
  u16* aDst = &aLds[w * 512];
  u16* bDst = &bLds[w * 512];
  f32x4 acc[4][4] = {};
  for (long k0 = 0; k0 < K; k0 += 32) {
    gl_lds16(Ap + k0, aDst);
    gl_lds16(Ap + 64 * K + k0, aDst + 2048);
    gl_lds16(Bp + k0, bDst);
    gl_lds16(Bp + 64 * K + k0, bDst + 2048);
    __syncthreads();
    bf16x8 av[4], bv[4];
#pragma unroll
    for (int i = 0; i < 4; ++i)
      av[i] = *(const bf16x8*)&aLds[(wm * 64 + i * 16 + l15) * 32 + lhi * 8];
#pragma unroll
    for (int j = 0; j < 4; ++j)
      bv[j] = *(const bf16x8*)&bLds[(wn * 64 + j * 16 + l15) * 32 + lhi * 8];
#pragma unroll
    for (int i = 0; i < 4; ++i)
#pragma unroll
      for (int j = 0; j < 4; ++j)
        acc[i][j] = __builtin_amdgcn_mfma_f32_16x16x32_bf16(av[i], bv[j], acc[i][j], 0, 0, 0);
    __syncthreads();
  }
#pragma unroll
  for (int j = 0; j < 4; ++j) {
    const long col = bn + wn * 64 + j * 16 + l15;
    const float bj = bias[col];
#pragma unroll
    for (int i = 0; i < 4; ++i) {
      const long row0 = bm + wm * 64 + i * 16 + lhi * 4;
#pragma unroll
      for (int r = 0; r < 4; ++r) {
        const float v = acc[i][j][r] + bj;
        const long idx = (row0 + r) * N + col;
        if constexpr (EPI == 0) {
          ((u16*)outp)[idx] = f2bf(v);
        } else if constexpr (EPI == 1) {
          ((float*)outp)[idx] = v + res[idx];
        } else {
          ((u16*)outp)[idx] = f2bf(v > 0.f ? v : 0.f);
        }
      }
    }
  }
}

// ---------------- V transpose: qkv -> vt[bh][d][kv] ----------------
__global__ __launch_bounds__(256) void vtrans(const u16* __restrict__ qkv,
                                              u16* __restrict__ vt) {
  const int t = threadIdx.x;
  const int bh = blockIdx.y, b = bh >> 4, h = bh & 15;
  const int kvb = blockIdx.x * 64;
  __shared__ u16 tile[64][72];
  const u16* src = qkv + ((size_t)(b * 2048 + kvb)) * 3072 + h * 192 + 128;
#pragma unroll
  for (int rr = 0; rr < 2; ++rr) {
    const int e = rr * 2048 + t * 8;
    const int kv = e >> 6, d = e & 63;
    *(bf16x8*)&tile[kv][d] = *(const bf16x8*)(src + (size_t)kv * 3072 + d);
  }
  __syncthreads();
#pragma unroll
  for (int rr = 0; rr < 2; ++rr) {
    const int e = rr * 2048 + t * 8;
    const int d = e >> 6, kv = e & 63;
    bf16x8 o;
#pragma unroll
    for (int j = 0; j < 8; ++j) o[j] = (short)tile[kv + j][d];
    *(bf16x8*)(vt + ((size_t)bh * 64 + d) * 2048 + kvb + kv) = o;
  }
}

// ---------------- Flash attention (LDS-staged K/V, swizzled, dbuf) -------
// grid (S/64, B*H), 4 waves, each wave owns 16 q rows; KV tiles of 64.
// LDS tiles are [64 rows][8 groups of 8 u16], group XOR-swizzled by (row&7).
// global_load_lds writes linearly; swizzle applied via per-lane GLOBAL src.
__global__ __launch_bounds__(256) void attn_k(const u16* __restrict__ qkv,
                                              const u16* __restrict__ vt,
                                              u16* __restrict__ ctx) {
  __shared__ u16 kt[2][4096];
  __shared__ u16 vtl[2][4096];
  __shared__ u16 plds[4][1024];
  const int t = threadIdx.x;
  const int lane = t & 63, w = t >> 6;
  const int l15 = lane & 15, lhi = lane >> 4;
  const int l7 = l15 & 7;
  const int bh = blockIdx.y, b = bh >> 4, h = bh & 15;
  const int q0 = blockIdx.x * 64 + w * 16;

  // Q fragments, pre-scaled by 1/sqrt(64) * log2(e) (softmax runs in exp2 space)
  const float qscale = 0.125f * 1.44269504f;
  const u16* qp = qkv + ((size_t)(b * 2048 + q0 + l15)) * 3072 + h * 192 + lhi * 8;
  bf16x8 qf0 = *(const bf16x8*)qp;
  bf16x8 qf1 = *(const bf16x8*)(qp + 32);
#pragma unroll
  for (int j = 0; j < 8; ++j) {
    qf0[j] = (short)f2bf(bf2f((u16)qf0[j]) * qscale);
    qf1[j] = (short)f2bf(bf2f((u16)qf1[j]) * qscale);
  }

  // staging geometry: thread t covers (row = t>>3 [+32 on call 1], group = t&7)
  const int srow = t >> 3, sgc = t & 7;
  const int sswz = (sgc ^ (srow & 7)) * 8;
  const u16* kg0 = qkv + ((size_t)(b * 2048 + srow)) * 3072 + h * 192 + 64 + sswz;
  const u16* vg0 = vt + (size_t)bh * 64 * 2048 + (size_t)srow * 2048 + sswz;
  u16* plds_w = &plds[w][0];

  f32x4 o[4] = {};
  float m[4], lsum[4];
#pragma unroll
  for (int r = 0; r < 4; ++r) { m[r] = -1e30f; lsum[r] = 0.f; }

#define STAGE(bufi, kv0i)                                              \
  do {                                                                 \
    const u16* ks_ = kg0 + (size_t)(kv0i) * 3072;                      \
    const u16* vs_ = vg0 + (kv0i);                                     \
    gl_lds16(ks_, &kt[bufi][w * 512]);                                 \
    gl_lds16(ks_ + (size_t)32 * 3072, &kt[bufi][2048 + w * 512]);      \
    gl_lds16(vs_, &vtl[bufi][w * 512]);                                \
    gl_lds16(vs_ + (size_t)32 * 2048, &vtl[bufi][2048 + w * 512]);     \
  } while (0)

  int buf = 0;
  STAGE(0, 0);
  for (int kv0 = 0; kv0 < 2048; kv0 += 64) {
    if (kv0 + 64 < 2048) STAGE(buf ^ 1, kv0 + 64);
    __syncthreads();
    // ---- QK^T (s in exp2 space) ----
    f32x4 s[4];
#pragma unroll
    for (int jt = 0; jt < 4; ++jt) {
      const int krow = (jt * 16 + l15) * 64;
      const bf16x8 k0 = *(const bf16x8*)&kt[buf][krow + ((0 * 4 + lhi) ^ l7) * 8];
      const bf16x8 k1 = *(const bf16x8*)&kt[buf][krow + ((1 * 4 + lhi) ^ l7) * 8];
      f32x4 z = {};
      z = __builtin_amdgcn_mfma_f32_16x16x32_bf16(qf0, k0, z, 0, 0, 0);
      s[jt] = __builtin_amdgcn_mfma_f32_16x16x32_bf16(qf1, k1, z, 0, 0, 0);
    }
    // ---- online softmax (exp2 space) ----
#pragma unroll
    for (int r = 0; r < 4; ++r) {
      float mt = fmaxf(fmaxf(s[0][r], s[1][r]), fmaxf(s[2][r], s[3][r]));
      mt = fmaxf(mt, __shfl_xor(mt, 1));
      mt = fmaxf(mt, __shfl_xor(mt, 2));
      mt = fmaxf(mt, __shfl_xor(mt, 4));
      mt = fmaxf(mt, __shfl_xor(mt, 8));
      const float mn = fmaxf(m[r], mt);
      const float sc = exp2f(m[r] - mn);
      m[r] = mn;
      float rsum = 0.f;
#pragma unroll
      for (int jt = 0; jt < 4; ++jt) {
        const float p = exp2f(s[jt][r] - mn);
        s[jt][r] = p;
        rsum += p;
      }
      rsum += __shfl_xor(rsum, 1);
      rsum += __shfl_xor(rsum, 2);
      rsum += __shfl_xor(rsum, 4);
      rsum += __shfl_xor(rsum, 8);
      lsum[r] = lsum[r] * sc + rsum;
      o[0][r] *= sc; o[1][r] *= sc; o[2][r] *= sc; o[3][r] *= sc;
    }
    // ---- P -> LDS (swizzled) ----
#pragma unroll
    for (int jt = 0; jt < 4; ++jt)
#pragma unroll
      for (int r = 0; r < 4; ++r) {
        const int prow = lhi * 4 + r;
        const int pidx = (prow * 64 + jt * 16 + l15) ^ ((prow & 7) << 3);
        plds_w[pidx] = f2bf(s[jt][r]);
      }
    asm volatile("" ::: "memory");
    // ---- PV ----
#pragma unroll
    for (int ks = 0; ks < 2; ++ks) {
      const bf16x8 pf =
          *(const bf16x8*)&plds_w[(l15 * 64 + ks * 32 + lhi * 8) ^ (l7 << 3)];
#pragma unroll
      for (int dt = 0; dt < 4; ++dt) {
        const bf16x8 vf =
            *(const bf16x8*)&vtl[buf][(dt * 16 + l15) * 64 + ((ks * 4 + lhi) ^ l7) * 8];
        o[dt] = __builtin_amdgcn_mfma_f32_16x16x32_bf16(pf, vf, o[dt], 0, 0, 0);
      }
    }
    asm volatile("" ::: "memory");
    __syncthreads();
    buf ^= 1;
  }
#undef STAGE
  float inv[4];
#pragma unroll
  for (int r = 0; r < 4; ++r) inv[r] = 1.f / lsum[r];
#pragma unroll
  for (int dt = 0; dt < 4; ++dt)
#pragma unroll
    for (int r = 0; r < 4; ++r) {
      const float v = o[dt][r] * inv[r];
      const int sg = q0 + lhi * 4 + r;
      ctx[((size_t)b * 2048 + sg) * 1024 + h * 64 + dt * 16 + l15] = f2bf(v);
    }
}

extern "C" void kernel_launch(void* const* d_in, const int* in_sizes, int n_in,
                              void* d_out, int out_size, void* d_ws, size_t ws_size,
                              hipStream_t stream) {
  const float* x     = (const float*)d_in[0];
  const float* w_qkv = (const float*)d_in[1];
  const float* b_qkv = (const float*)d_in[2];
  const float* w_out = (const float*)d_in[3];
  const float* b_out = (const float*)d_in[4];
  const float* w1    = (const float*)d_in[5];
  const float* b1    = (const float*)d_in[6];
  const float* w2    = (const float*)d_in[7];
  const float* b2    = (const float*)d_in[8];
  const float* ln1g  = (const float*)d_in[9];
  const float* ln1b  = (const float*)d_in[10];
  const float* ln2g  = (const float*)d_in[11];
  const float* ln2b  = (const float*)d_in[12];
  float* out = (float*)d_out;

  u16* wqkv_b = (u16*)d_ws;                       // 3072*1024
  u16* wout_b = wqkv_b + (size_t)3072 * 1024;     // 1024*1024
  u16* w1_b   = wout_b + (size_t)1024 * 1024;     // 4096*1024
  u16* w2_b   = w1_b + (size_t)4096 * 1024;       // 1024*4096
  u16* r1     = w2_b + (size_t)1024 * 4096;       // 4096*1024: h1 / ctx / h2
  u16* r2     = r1 + (size_t)4096 * 1024;         // 4096*4096: qkv+vt, then hff
  u16* qkvb   = r2;
  u16* vtb    = r2 + (size_t)4096 * 3072;
  float* x2   = (float*)(r2 + (size_t)4096 * 4096); // 4096*1024 f32

  // weight conversion
  cvt_f32_bf16<<<1024, 256, 0, stream>>>(w_qkv, wqkv_b, 3072 * 1024 / 4);
  cvt_f32_bf16<<<1024, 256, 0, stream>>>(w_out, wout_b, 1024 * 1024 / 4);
  cvt_f32_bf16<<<1024, 256, 0, stream>>>(w1, w1_b, 4096 * 1024 / 4);
  cvt_f32_bf16<<<1024, 256, 0, stream>>>(w2, w2_b, 1024 * 4096 / 4);

  // LN1 -> h1 (r1)
  ln_k<<<4096, 256, 0, stream>>>(x, ln1g, ln1b, r1);
  // QKV GEMM: [4096,1024] x [3072,1024]^T -> qkv bf16
  gemm_nt<0><<<dim3(24, 32), 256, 0, stream>>>(r1, wqkv_b, b_qkv, nullptr, qkvb, 3072, 1024);
  // V transpose
  vtrans<<<dim3(32, 32), 256, 0, stream>>>(qkvb, vtb);
  // attention -> ctx (r1)
  attn_k<<<dim3(32, 32), 256, 0, stream>>>(qkvb, vtb, r1);
  // out-proj + residual -> x2 (f32)
  gemm_nt<1><<<dim3(8, 32), 256, 0, stream>>>(r1, wout_b, b_out, x, x2, 1024, 1024);
  // LN2 -> h2 (r1)
  ln_k<<<4096, 256, 0, stream>>>(x2, ln2g, ln2b, r1);
  // MLP1 + ReLU -> hff (r2)
  gemm_nt<2><<<dim3(32, 32), 256, 0, stream>>>(r1, w1_b, b1, nullptr, r2, 4096, 1024);
  // MLP2 + residual -> out (f32)
  gemm_nt<1><<<dim3(8, 32), 256, 0, stream>>>(r2, w2_b, b2, x2, out, 1024, 4096);
}

// Round 3
// 353.594 us; speedup vs baseline: 1.5644x; 1.0987x over previous
//
#include <hip/hip_runtime.h>
#include <hip/hip_bf16.h>

typedef __attribute__((ext_vector_type(8))) short bf16x8;
typedef __attribute__((ext_vector_type(4))) float f32x4;
typedef __attribute__((ext_vector_type(4))) unsigned short u16x4;
typedef unsigned short u16;

__device__ __forceinline__ u16 f2bf(float f) {
  unsigned u = __builtin_bit_cast(unsigned, f);
  u += 0x7fffu + ((u >> 16) & 1u);
  return (u16)(u >> 16);
}
__device__ __forceinline__ float bf2f(u16 u) {
  unsigned v = ((unsigned)u) << 16;
  return __builtin_bit_cast(float, v);
}

__device__ __forceinline__ void gl_lds16(const void* g, void* l) {
  __builtin_amdgcn_global_load_lds((const __attribute__((address_space(1))) void*)g,
                                   (__attribute__((address_space(3))) void*)l,
                                   16, 0, 0);
}

// ---------------- f32 -> bf16 convert ----------------
__global__ __launch_bounds__(256) void cvt_f32_bf16(const float* __restrict__ in,
                                                    u16* __restrict__ out, int n4) {
  int i = blockIdx.x * 256 + threadIdx.x;
  const int stride = gridDim.x * 256;
  for (; i < n4; i += stride) {
    float4 v = ((const float4*)in)[i];
    u16x4 o;
    o.x = f2bf(v.x); o.y = f2bf(v.y); o.z = f2bf(v.z); o.w = f2bf(v.w);
    ((u16x4*)out)[i] = o;
  }
}

// ---------------- LayerNorm: f32 in, bf16 out (D=1024) ----------------
__global__ __launch_bounds__(256) void ln_k(const float* __restrict__ x,
                                            const float* __restrict__ g,
                                            const float* __restrict__ b,
                                            u16* __restrict__ out) {
  const int row = blockIdx.x;
  const int t = threadIdx.x;
  const int lane = t & 63, w = t >> 6;
  const float4 v = ((const float4*)(x + (size_t)row * 1024))[t];
  float s = v.x + v.y + v.z + v.w;
  float q = v.x * v.x + v.y * v.y + v.z * v.z + v.w * v.w;
#pragma unroll
  for (int off = 32; off; off >>= 1) {
    s += __shfl_down(s, off);
    q += __shfl_down(q, off);
  }
  __shared__ float red[8];
  if (lane == 0) { red[w] = s; red[4 + w] = q; }
  __syncthreads();
  s = red[0] + red[1] + red[2] + red[3];
  q = red[4] + red[5] + red[6] + red[7];
  const float mu = s * (1.f / 1024.f);
  const float var = q * (1.f / 1024.f) - mu * mu;
  const float rs = rsqrtf(var + 1e-5f);
  const float4 gv = ((const float4*)g)[t];
  const float4 bv = ((const float4*)b)[t];
  u16x4 o;
  o.x = f2bf((v.x - mu) * rs * gv.x + bv.x);
  o.y = f2bf((v.y - mu) * rs * gv.y + bv.y);
  o.z = f2bf((v.z - mu) * rs * gv.z + bv.z);
  o.w = f2bf((v.w - mu) * rs * gv.w + bv.w);
  ((u16x4*)(out + (size_t)row * 1024))[t] = o;
}

// ---------------- NT GEMM: C[M,N] = A[M,K] * B[N,K]^T (+bias, epilogue) ---
// EPI 0: bf16(v+bias)   1: f32 v+bias+res   2: bf16(relu(v+bias))
template <int EPI>
__global__ __launch_bounds__(256) void gemm_nt(const u16* __restrict__ A,
                                               const u16* __restrict__ B,
                                               const float* __restrict__ bias,
                                               const float* __restrict__ res,
                                               void* __restrict__ outp,
                                               int N, long K) {
  __shared__ u16 aLds[4096];
  __shared__ u16 bLds[4096];
  const int t = threadIdx.x;
  const int lane = t & 63, w = t >> 6;
  const int wm = w >> 1, wn = w & 1;
  const int l15 = lane & 15, lhi = lane >> 4;
  const long bm = (long)blockIdx.y * 128, bn = (long)blockIdx.x * 128;
  const int e0 = t * 8;
  const int r0 = e0 >> 5, c0 = e0 & 31;
  const u16* Ap = A + (bm + r0) * K + c0;
  const u16* Bp = B + (bn + r0) * K + c0;
  u16* aDst = &aLds[w * 512];
  u16* bDst = &bLds[w * 512];
  f32x4 acc[4][4] = {};
  for (long k0 = 0; k0 < K; k0 += 32) {
    gl_lds16(Ap + k0, aDst);
    gl_lds16(Ap + 64 * K + k0, aDst + 2048);
    gl_lds16(Bp + k0, bDst);
    gl_lds16(Bp + 64 * K + k0, bDst + 2048);
    __syncthreads();
    bf16x8 av[4], bv[4];
#pragma unroll
    for (int i = 0; i < 4; ++i)
      av[i] = *(const bf16x8*)&aLds[(wm * 64 + i * 16 + l15) * 32 + lhi * 8];
#pragma unroll
    for (int j = 0; j < 4; ++j)
      bv[j] = *(const bf16x8*)&bLds[(wn * 64 + j * 16 + l15) * 32 + lhi * 8];
#pragma unroll
    for (int i = 0; i < 4; ++i)
#pragma unroll
      for (int j = 0; j < 4; ++j)
        acc[i][j] = __builtin_amdgcn_mfma_f32_16x16x32_bf16(av[i], bv[j], acc[i][j], 0, 0, 0);
    __syncthreads();
  }
#pragma unroll
  for (int j = 0; j < 4; ++j) {
    const long col = bn + wn * 64 + j * 16 + l15;
    const float bj = bias[col];
#pragma unroll
    for (int i = 0; i < 4; ++i) {
      const long row0 = bm + wm * 64 + i * 16 + lhi * 4;
#pragma unroll
      for (int r = 0; r < 4; ++r) {
        const float v = acc[i][j][r] + bj;
        const long idx = (row0 + r) * N + col;
        if constexpr (EPI == 0) {
          ((u16*)outp)[idx] = f2bf(v);
        } else if constexpr (EPI == 1) {
          ((float*)outp)[idx] = v + res[idx];
        } else {
          ((u16*)outp)[idx] = f2bf(v > 0.f ? v : 0.f);
        }
      }
    }
  }
}

// ---------------- V transpose: qkv -> vt[bh][d][kv] ----------------
__global__ __launch_bounds__(256) void vtrans(const u16* __restrict__ qkv,
                                              u16* __restrict__ vt) {
  const int t = threadIdx.x;
  const int bh = blockIdx.y, b = bh >> 4, h = bh & 15;
  const int kvb = blockIdx.x * 64;
  __shared__ u16 tile[64][72];
  const u16* src = qkv + ((size_t)(b * 2048 + kvb)) * 3072 + h * 192 + 128;
#pragma unroll
  for (int rr = 0; rr < 2; ++rr) {
    const int e = rr * 2048 + t * 8;
    const int kv = e >> 6, d = e & 63;
    *(bf16x8*)&tile[kv][d] = *(const bf16x8*)(src + (size_t)kv * 3072 + d);
  }
  __syncthreads();
#pragma unroll
  for (int rr = 0; rr < 2; ++rr) {
    const int e = rr * 2048 + t * 8;
    const int d = e >> 6, kv = e & 63;
    bf16x8 o;
#pragma unroll
    for (int j = 0; j < 8; ++j) o[j] = (short)tile[kv + j][d];
    *(bf16x8*)(vt + ((size_t)bh * 64 + d) * 2048 + kvb + kv) = o;
  }
}

// ---------------- Flash attention (swapped-operand, lane-local softmax) ---
// grid (S/64, B*H), 4 waves, each wave owns 16 q rows; KV tiles of 64.
// QK^T computed as mfma(K,Q) -> lane holds S[q=l15][kv=jt*16+lhi*4+r]:
// row max/sum are in-register trees + 2 shfl_xor over lhi.
// PV computed as mfma(Vt,P) -> o lane-local in q; defer-max (THR=8, log2).
__global__ __launch_bounds__(256) void attn_k(const u16* __restrict__ qkv,
                                              const u16* __restrict__ vt,
                                              u16* __restrict__ ctx) {
  __shared__ u16 kt[2][4096];
  __shared__ u16 vtl[2][4096];
  __shared__ u16 plds[4][1024];
  const int t = threadIdx.x;
  const int lane = t & 63, w = t >> 6;
  const int l15 = lane & 15, lhi = lane >> 4;
  const int l7 = l15 & 7;
  const int bh = blockIdx.y, b = bh >> 4, h = bh & 15;
  const int q0 = blockIdx.x * 64 + w * 16;

  // Q fragments, pre-scaled by 1/sqrt(64) * log2(e) (softmax in exp2 space)
  const float qscale = 0.125f * 1.44269504f;
  const u16* qp = qkv + ((size_t)(b * 2048 + q0 + l15)) * 3072 + h * 192 + lhi * 8;
  bf16x8 qf0 = *(const bf16x8*)qp;
  bf16x8 qf1 = *(const bf16x8*)(qp + 32);
#pragma unroll
  for (int j = 0; j < 8; ++j) {
    qf0[j] = (short)f2bf(bf2f((u16)qf0[j]) * qscale);
    qf1[j] = (short)f2bf(bf2f((u16)qf1[j]) * qscale);
  }

  // staging geometry: thread t covers (row = t>>3 [+32 on call 1], group = t&7)
  const int srow = t >> 3, sgc = t & 7;
  const int sswz = (sgc ^ (srow & 7)) * 8;
  const u16* kg0 = qkv + ((size_t)(b * 2048 + srow)) * 3072 + h * 192 + 64 + sswz;
  const u16* vg0 = vt + (size_t)bh * 64 * 2048 + (size_t)srow * 2048 + sswz;
  u16* plds_w = &plds[w][0];

  f32x4 o[4] = {};
  float m = -1e30f, lsum = 0.f;

#define STAGE(bufi, kv0i)                                              \
  do {                                                                 \
    const u16* ks_ = kg0 + (size_t)(kv0i) * 3072;                      \
    const u16* vs_ = vg0 + (kv0i);                                     \
    gl_lds16(ks_, &kt[bufi][w * 512]);                                 \
    gl_lds16(ks_ + (size_t)32 * 3072, &kt[bufi][2048 + w * 512]);      \
    gl_lds16(vs_, &vtl[bufi][w * 512]);                                \
    gl_lds16(vs_ + (size_t)32 * 2048, &vtl[bufi][2048 + w * 512]);     \
  } while (0)

  int buf = 0;
  STAGE(0, 0);
  for (int kv0 = 0; kv0 < 2048; kv0 += 64) {
    if (kv0 + 64 < 2048) STAGE(buf ^ 1, kv0 + 64);
    __syncthreads();
    // ---- QK^T swapped: s[jt][r] = S[q=l15][kv=jt*16+lhi*4+r] ----
    f32x4 s[4];
#pragma unroll
    for (int jt = 0; jt < 4; ++jt) {
      const int krow = (jt * 16 + l15) * 64;
      const bf16x8 k0 = *(const bf16x8*)&kt[buf][krow + ((0 * 4 + lhi) ^ l7) * 8];
      const bf16x8 k1 = *(const bf16x8*)&kt[buf][krow + ((1 * 4 + lhi) ^ l7) * 8];
      f32x4 z = {};
      z = __builtin_amdgcn_mfma_f32_16x16x32_bf16(k0, qf0, z, 0, 0, 0);
      s[jt] = __builtin_amdgcn_mfma_f32_16x16x32_bf16(k1, qf1, z, 0, 0, 0);
    }
    // ---- lane-local online softmax (exp2 space) ----
    float px0 = fmaxf(fmaxf(s[0][0], s[0][1]), fmaxf(s[0][2], s[0][3]));
    float px1 = fmaxf(fmaxf(s[1][0], s[1][1]), fmaxf(s[1][2], s[1][3]));
    float px2 = fmaxf(fmaxf(s[2][0], s[2][1]), fmaxf(s[2][2], s[2][3]));
    float px3 = fmaxf(fmaxf(s[3][0], s[3][1]), fmaxf(s[3][2], s[3][3]));
    float pmax = fmaxf(fmaxf(px0, px1), fmaxf(px2, px3));
    pmax = fmaxf(pmax, __shfl_xor(pmax, 16));
    pmax = fmaxf(pmax, __shfl_xor(pmax, 32));
    if (!__all(pmax <= m + 8.f)) {
      const float mn = fmaxf(m, pmax);
      const float sc = exp2f(m - mn);
      m = mn;
      lsum *= sc;
#pragma unroll
      for (int dt = 0; dt < 4; ++dt)
#pragma unroll
        for (int r = 0; r < 4; ++r) o[dt][r] *= sc;
    }
    float rsum = 0.f;
    u16x4 pk[4];
#pragma unroll
    for (int jt = 0; jt < 4; ++jt)
#pragma unroll
      for (int r = 0; r < 4; ++r) {
        const float p = exp2f(s[jt][r] - m);
        rsum += p;
        pk[jt][r] = f2bf(p);
      }
    rsum += __shfl_xor(rsum, 16);
    rsum += __shfl_xor(rsum, 32);
    lsum += rsum;
    // ---- P -> LDS (packed b64 writes, swizzled) ----
#pragma unroll
    for (int jt = 0; jt < 4; ++jt)
      *(u16x4*)&plds_w[(l15 * 64 + jt * 16 + lhi * 4) ^ (l7 << 3)] = pk[jt];
    asm volatile("" ::: "memory");
    // ---- PV swapped: o[dt][r] = O[q=l15][d=dt*16+lhi*4+r] ----
#pragma unroll
    for (int ks = 0; ks < 2; ++ks) {
      const bf16x8 pf =
          *(const bf16x8*)&plds_w[(l15 * 64 + ks * 32 + lhi * 8) ^ (l7 << 3)];
#pragma unroll
      for (int dt = 0; dt < 4; ++dt) {
        const bf16x8 vf =
            *(const bf16x8*)&vtl[buf][(dt * 16 + l15) * 64 + ((ks * 4 + lhi) ^ l7) * 8];
        o[dt] = __builtin_amdgcn_mfma_f32_16x16x32_bf16(vf, pf, o[dt], 0, 0, 0);
      }
    }
    asm volatile("" ::: "memory");
    __syncthreads();
    buf ^= 1;
  }
#undef STAGE
  const float inv = 1.f / lsum;
  u16* crow = ctx + ((size_t)(b * 2048 + q0 + l15)) * 1024 + h * 64;
#pragma unroll
  for (int dt = 0; dt < 4; ++dt) {
    u16x4 ov;
#pragma unroll
    for (int r = 0; r < 4; ++r) ov[r] = f2bf(o[dt][r] * inv);
    *(u16x4*)&crow[dt * 16 + lhi * 4] = ov;
  }
}

extern "C" void kernel_launch(void* const* d_in, const int* in_sizes, int n_in,
                              void* d_out, int out_size, void* d_ws, size_t ws_size,
                              hipStream_t stream) {
  const float* x     = (const float*)d_in[0];
  const float* w_qkv = (const float*)d_in[1];
  const float* b_qkv = (const float*)d_in[2];
  const float* w_out = (const float*)d_in[3];
  const float* b_out = (const float*)d_in[4];
  const float* w1    = (const float*)d_in[5];
  const float* b1    = (const float*)d_in[6];
  const float* w2    = (const float*)d_in[7];
  const float* b2    = (const float*)d_in[8];
  const float* ln1g  = (const float*)d_in[9];
  const float* ln1b  = (const float*)d_in[10];
  const float* ln2g  = (const float*)d_in[11];
  const float* ln2b  = (const float*)d_in[12];
  float* out = (float*)d_out;

  u16* wqkv_b = (u16*)d_ws;                       // 3072*1024
  u16* wout_b = wqkv_b + (size_t)3072 * 1024;     // 1024*1024
  u16* w1_b   = wout_b + (size_t)1024 * 1024;     // 4096*1024
  u16* w2_b   = w1_b + (size_t)4096 * 1024;       // 1024*4096
  u16* r1     = w2_b + (size_t)1024 * 4096;       // 4096*1024: h1 / ctx / h2
  u16* r2     = r1 + (size_t)4096 * 1024;         // 4096*4096: qkv+vt, then hff
  u16* qkvb   = r2;
  u16* vtb    = r2 + (size_t)4096 * 3072;
  float* x2   = (float*)(r2 + (size_t)4096 * 4096); // 4096*1024 f32

  // weight conversion
  cvt_f32_bf16<<<1024, 256, 0, stream>>>(w_qkv, wqkv_b, 3072 * 1024 / 4);
  cvt_f32_bf16<<<1024, 256, 0, stream>>>(w_out, wout_b, 1024 * 1024 / 4);
  cvt_f32_bf16<<<1024, 256, 0, stream>>>(w1, w1_b, 4096 * 1024 / 4);
  cvt_f32_bf16<<<1024, 256, 0, stream>>>(w2, w2_b, 1024 * 4096 / 4);

  // LN1 -> h1 (r1)
  ln_k<<<4096, 256, 0, stream>>>(x, ln1g, ln1b, r1);
  // QKV GEMM: [4096,1024] x [3072,1024]^T -> qkv bf16
  gemm_nt<0><<<dim3(24, 32), 256, 0, stream>>>(r1, wqkv_b, b_qkv, nullptr, qkvb, 3072, 1024);
  // V transpose
  vtrans<<<dim3(32, 32), 256, 0, stream>>>(qkvb, vtb);
  // attention -> ctx (r1)
  attn_k<<<dim3(32, 32), 256, 0, stream>>>(qkvb, vtb, r1);
  // out-proj + residual -> x2 (f32)
  gemm_nt<1><<<dim3(8, 32), 256, 0, stream>>>(r1, wout_b, b_out, x, x2, 1024, 1024);
  // LN2 -> h2 (r1)
  ln_k<<<4096, 256, 0, stream>>>(x2, ln2g, ln2b, r1);
  // MLP1 + ReLU -> hff (r2)
  gemm_nt<2><<<dim3(32, 32), 256, 0, stream>>>(r1, w1_b, b1, nullptr, r2, 4096, 1024);
  // MLP2 + residual -> out (f32)
  gemm_nt<1><<<dim3(8, 32), 256, 0, stream>>>(r2, w2_b, b2, x2, out, 1024, 4096);
}

// Round 4
// 273.153 us; speedup vs baseline: 2.0251x; 1.2945x over previous
//
#include <hip/hip_runtime.h>
#include <hip/hip_bf16.h>

typedef __attribute__((ext_vector_type(8))) short bf16x8;
typedef __attribute__((ext_vector_type(4))) float f32x4;
typedef __attribute__((ext_vector_type(4))) unsigned short u16x4;
typedef unsigned short u16;

__device__ __forceinline__ u16 f2bf(float f) {
  unsigned u = __builtin_bit_cast(unsigned, f);
  u += 0x7fffu + ((u >> 16) & 1u);
  return (u16)(u >> 16);
}
__device__ __forceinline__ float bf2f(u16 u) {
  unsigned v = ((unsigned)u) << 16;
  return __builtin_bit_cast(float, v);
}

__device__ __forceinline__ void gl_lds16(const void* g, void* l) {
  __builtin_amdgcn_global_load_lds((const __attribute__((address_space(1))) void*)g,
                                   (__attribute__((address_space(3))) void*)l,
                                   16, 0, 0);
}

__device__ __forceinline__ void bar() {
  asm volatile("" ::: "memory");
  __builtin_amdgcn_s_barrier();
  asm volatile("" ::: "memory");
}

// ---------------- f32 -> bf16 convert ----------------
__global__ __launch_bounds__(256) void cvt_f32_bf16(const float* __restrict__ in,
                                                    u16* __restrict__ out, int n4) {
  int i = blockIdx.x * 256 + threadIdx.x;
  const int stride = gridDim.x * 256;
  for (; i < n4; i += stride) {
    float4 v = ((const float4*)in)[i];
    u16x4 o;
    o.x = f2bf(v.x); o.y = f2bf(v.y); o.z = f2bf(v.z); o.w = f2bf(v.w);
    ((u16x4*)out)[i] = o;
  }
}

// ---------------- LayerNorm: f32 in, bf16 out (D=1024) ----------------
__global__ __launch_bounds__(256) void ln_k(const float* __restrict__ x,
                                            const float* __restrict__ g,
                                            const float* __restrict__ b,
                                            u16* __restrict__ out) {
  const int row = blockIdx.x;
  const int t = threadIdx.x;
  const int lane = t & 63, w = t >> 6;
  const float4 v = ((const float4*)(x + (size_t)row * 1024))[t];
  float s = v.x + v.y + v.z + v.w;
  float q = v.x * v.x + v.y * v.y + v.z * v.z + v.w * v.w;
#pragma unroll
  for (int off = 32; off; off >>= 1) {
    s += __shfl_down(s, off);
    q += __shfl_down(q, off);
  }
  __shared__ float red[8];
  if (lane == 0) { red[w] = s; red[4 + w] = q; }
  __syncthreads();
  s = red[0] + red[1] + red[2] + red[3];
  q = red[4] + red[5] + red[6] + red[7];
  const float mu = s * (1.f / 1024.f);
  const float var = q * (1.f / 1024.f) - mu * mu;
  const float rs = rsqrtf(var + 1e-5f);
  const float4 gv = ((const float4*)g)[t];
  const float4 bv = ((const float4*)b)[t];
  u16x4 o;
  o.x = f2bf((v.x - mu) * rs * gv.x + bv.x);
  o.y = f2bf((v.y - mu) * rs * gv.y + bv.y);
  o.z = f2bf((v.z - mu) * rs * gv.z + bv.z);
  o.w = f2bf((v.w - mu) * rs * gv.w + bv.w);
  ((u16x4*)(out + (size_t)row * 1024))[t] = o;
}

// ---- NT GEMM, 3-buffer rotation, counted vmcnt, T2 swizzle, XCD swizzle ----
// C[M,N] = A[M,K]*B[N,K]^T (+bias, epilogue). BK=32.
// LDS slot s (16B) of a tile holds global 16B-group g = (s&3) ^ ((s>>3)&3)
// of row s>>2 (pre-swizzled global source, linear gl_lds dest).
// EPI 0: bf16(v+bias)   1: f32 v+bias+res   2: bf16(relu(v+bias))
template <int BM, int BN, int TH, int WN, int MR, int NR, int EPI>
__global__ __launch_bounds__(TH, 2) void gemm_rot(const u16* __restrict__ A,
                                                  const u16* __restrict__ B,
                                                  const float* __restrict__ bias,
                                                  const float* __restrict__ res,
                                                  void* __restrict__ outp,
                                                  const int N, const int K) {
  constexpr int AELEMS = BM * 32;  // u16 elems per A tile (BK=32)
  constexpr int BELEMS = BN * 32;
  __shared__ u16 lds[3][AELEMS + BELEMS];
  const int t = threadIdx.x;
  const int lane = t & 63, w = t >> 6;
  const int wm = w / WN, wn = w % WN;
  const int l15 = lane & 15, lhi = lane >> 4;
  // bijective XCD swizzle (all grids have nwg % 8 == 0)
  const int nbx = gridDim.x;
  const int nwg = nbx * gridDim.y;
  const int orig = blockIdx.y * nbx + blockIdx.x;
  const int cpx = nwg >> 3;
  const int lid = (orig & 7) * cpx + (orig >> 3);
  const long bm = (long)(lid / nbx) * BM, bn = (long)(lid % nbx) * BN;
  const u16* Ab = A + bm * K;
  const u16* Bb = B + bn * K;
  const int nk = K >> 5;

  // staging geometry: per call j, this thread fills LDS slot (j*TH + t)
  const int s0 = t, s1 = TH + t;
  const int ar0 = s0 >> 2, ag0 = (s0 & 3) ^ ((ar0 >> 1) & 3);
  const int ar1 = s1 >> 2, ag1 = (s1 & 3) ^ ((ar1 >> 1) & 3);

#define STAGE(kt, bufi)                                                       \
  do {                                                                        \
    const long kk_ = (long)(kt) << 5;                                         \
    gl_lds16(Ab + (size_t)ar0 * K + kk_ + ag0 * 8, &lds[bufi][(size_t)(w * 64) * 8]);            \
    gl_lds16(Ab + (size_t)ar1 * K + kk_ + ag1 * 8, &lds[bufi][(size_t)(TH + w * 64) * 8]);       \
    gl_lds16(Bb + (size_t)ar0 * K + kk_ + ag0 * 8, &lds[bufi][AELEMS + (size_t)(w * 64) * 8]);   \
    gl_lds16(Bb + (size_t)ar1 * K + kk_ + ag1 * 8, &lds[bufi][AELEMS + (size_t)(TH + w * 64) * 8]); \
  } while (0)

  f32x4 acc[MR][NR] = {};
  STAGE(0, 0);
  STAGE(1, 1);
  STAGE(2, 2);
  for (int i = 0; i < nk; ++i) {
    if (i + 2 < nk)      asm volatile("s_waitcnt vmcnt(8)" ::: "memory");
    else if (i + 1 < nk) asm volatile("s_waitcnt vmcnt(4)" ::: "memory");
    else                 asm volatile("s_waitcnt vmcnt(0)" ::: "memory");
    bar();
    const u16* bufA = lds[i % 3];
    const u16* bufB = bufA + AELEMS;
    bf16x8 av[MR], bv[NR];
#pragma unroll
    for (int ii = 0; ii < MR; ++ii) {
      const int R = wm * (MR * 16) + ii * 16 + l15;
      av[ii] = *(const bf16x8*)&bufA[R * 32 + ((lhi ^ ((R >> 1) & 3)) << 3)];
    }
#pragma unroll
    for (int jj = 0; jj < NR; ++jj) {
      const int R = wn * (NR * 16) + jj * 16 + l15;
      bv[jj] = *(const bf16x8*)&bufB[R * 32 + ((lhi ^ ((R >> 1) & 3)) << 3)];
    }
    __builtin_amdgcn_s_setprio(1);
#pragma unroll
    for (int ii = 0; ii < MR; ++ii)
#pragma unroll
      for (int jj = 0; jj < NR; ++jj)
        acc[ii][jj] = __builtin_amdgcn_mfma_f32_16x16x32_bf16(av[ii], bv[jj], acc[ii][jj], 0, 0, 0);
    __builtin_amdgcn_s_setprio(0);
    bar();
    if (i + 3 < nk) STAGE(i + 3, i % 3);
  }
#undef STAGE
#pragma unroll
  for (int jj = 0; jj < NR; ++jj) {
    const long col = bn + wn * (NR * 16) + jj * 16 + l15;
    const float bj = bias[col];
#pragma unroll
    for (int ii = 0; ii < MR; ++ii) {
      const long row0 = bm + wm * (MR * 16) + ii * 16 + lhi * 4;
#pragma unroll
      for (int r = 0; r < 4; ++r) {
        const float v = acc[ii][jj][r] + bj;
        const long idx = (row0 + r) * N + col;
        if constexpr (EPI == 0) {
          ((u16*)outp)[idx] = f2bf(v);
        } else if constexpr (EPI == 1) {
          ((float*)outp)[idx] = v + res[idx];
        } else {
          ((u16*)outp)[idx] = f2bf(v > 0.f ? v : 0.f);
        }
      }
    }
  }
}

// ---------------- V transpose: qkv -> vt[bh][d][kv] ----------------
__global__ __launch_bounds__(256) void vtrans(const u16* __restrict__ qkv,
                                              u16* __restrict__ vt) {
  const int t = threadIdx.x;
  const int bh = blockIdx.y, b = bh >> 4, h = bh & 15;
  const int kvb = blockIdx.x * 64;
  __shared__ u16 tile[64][72];
  const u16* src = qkv + ((size_t)(b * 2048 + kvb)) * 3072 + h * 192 + 128;
#pragma unroll
  for (int rr = 0; rr < 2; ++rr) {
    const int e = rr * 2048 + t * 8;
    const int kv = e >> 6, d = e & 63;
    *(bf16x8*)&tile[kv][d] = *(const bf16x8*)(src + (size_t)kv * 3072 + d);
  }
  __syncthreads();
#pragma unroll
  for (int rr = 0; rr < 2; ++rr) {
    const int e = rr * 2048 + t * 8;
    const int d = e >> 6, kv = e & 63;
    bf16x8 o;
#pragma unroll
    for (int j = 0; j < 8; ++j) o[j] = (short)tile[kv + j][d];
    *(bf16x8*)(vt + ((size_t)bh * 64 + d) * 2048 + kvb + kv) = o;
  }
}

// ---------------- Flash attention (swapped-operand, lane-local softmax) ---
__global__ __launch_bounds__(256) void attn_k(const u16* __restrict__ qkv,
                                              const u16* __restrict__ vt,
                                              u16* __restrict__ ctx) {
  __shared__ u16 kt[2][4096];
  __shared__ u16 vtl[2][4096];
  __shared__ u16 plds[4][1024];
  const int t = threadIdx.x;
  const int lane = t & 63, w = t >> 6;
  const int l15 = lane & 15, lhi = lane >> 4;
  const int l7 = l15 & 7;
  const int bh = blockIdx.y, b = bh >> 4, h = bh & 15;
  const int q0 = blockIdx.x * 64 + w * 16;

  const float qscale = 0.125f * 1.44269504f;
  const u16* qp = qkv + ((size_t)(b * 2048 + q0 + l15)) * 3072 + h * 192 + lhi * 8;
  bf16x8 qf0 = *(const bf16x8*)qp;
  bf16x8 qf1 = *(const bf16x8*)(qp + 32);
#pragma unroll
  for (int j = 0; j < 8; ++j) {
    qf0[j] = (short)f2bf(bf2f((u16)qf0[j]) * qscale);
    qf1[j] = (short)f2bf(bf2f((u16)qf1[j]) * qscale);
  }

  const int srow = t >> 3, sgc = t & 7;
  const int sswz = (sgc ^ (srow & 7)) * 8;
  const u16* kg0 = qkv + ((size_t)(b * 2048 + srow)) * 3072 + h * 192 + 64 + sswz;
  const u16* vg0 = vt + (size_t)bh * 64 * 2048 + (size_t)srow * 2048 + sswz;
  u16* plds_w = &plds[w][0];

  f32x4 o[4] = {};
  float m = -1e30f, lsum = 0.f;

#define STAGE(bufi, kv0i)                                              \
  do {                                                                 \
    const u16* ks_ = kg0 + (size_t)(kv0i) * 3072;                      \
    const u16* vs_ = vg0 + (kv0i);                                     \
    gl_lds16(ks_, &kt[bufi][w * 512]);                                 \
    gl_lds16(ks_ + (size_t)32 * 3072, &kt[bufi][2048 + w * 512]);      \
    gl_lds16(vs_, &vtl[bufi][w * 512]);                                \
    gl_lds16(vs_ + (size_t)32 * 2048, &vtl[bufi][2048 + w * 512]);     \
  } while (0)

  int buf = 0;
  STAGE(0, 0);
  for (int kv0 = 0; kv0 < 2048; kv0 += 64) {
    if (kv0 + 64 < 2048) STAGE(buf ^ 1, kv0 + 64);
    __syncthreads();
    f32x4 s[4];
#pragma unroll
    for (int jt = 0; jt < 4; ++jt) {
      const int krow = (jt * 16 + l15) * 64;
      const bf16x8 k0 = *(const bf16x8*)&kt[buf][krow + ((0 * 4 + lhi) ^ l7) * 8];
      const bf16x8 k1 = *(const bf16x8*)&kt[buf][krow + ((1 * 4 + lhi) ^ l7) * 8];
      f32x4 z = {};
      z = __builtin_amdgcn_mfma_f32_16x16x32_bf16(k0, qf0, z, 0, 0, 0);
      s[jt] = __builtin_amdgcn_mfma_f32_16x16x32_bf16(k1, qf1, z, 0, 0, 0);
    }
    float px0 = fmaxf(fmaxf(s[0][0], s[0][1]), fmaxf(s[0][2], s[0][3]));
    float px1 = fmaxf(fmaxf(s[1][0], s[1][1]), fmaxf(s[1][2], s[1][3]));
    float px2 = fmaxf(fmaxf(s[2][0], s[2][1]), fmaxf(s[2][2], s[2][3]));
    float px3 = fmaxf(fmaxf(s[3][0], s[3][1]), fmaxf(s[3][2], s[3][3]));
    float pmax = fmaxf(fmaxf(px0, px1), fmaxf(px2, px3));
    pmax = fmaxf(pmax, __shfl_xor(pmax, 16));
    pmax = fmaxf(pmax, __shfl_xor(pmax, 32));
    if (!__all(pmax <= m + 8.f)) {
      const float mn = fmaxf(m, pmax);
      const float sc = exp2f(m - mn);
      m = mn;
      lsum *= sc;
#pragma unroll
      for (int dt = 0; dt < 4; ++dt)
#pragma unroll
        for (int r = 0; r < 4; ++r) o[dt][r] *= sc;
    }
    float rsum = 0.f;
    u16x4 pk[4];
#pragma unroll
    for (int jt = 0; jt < 4; ++jt)
#pragma unroll
      for (int r = 0; r < 4; ++r) {
        const float p = exp2f(s[jt][r] - m);
        rsum += p;
        pk[jt][r] = f2bf(p);
      }
    rsum += __shfl_xor(rsum, 16);
    rsum += __shfl_xor(rsum, 32);
    lsum += rsum;
#pragma unroll
    for (int jt = 0; jt < 4; ++jt)
      *(u16x4*)&plds_w[(l15 * 64 + jt * 16 + lhi * 4) ^ (l7 << 3)] = pk[jt];
    asm volatile("" ::: "memory");
#pragma unroll
    for (int ks = 0; ks < 2; ++ks) {
      const bf16x8 pf =
          *(const bf16x8*)&plds_w[(l15 * 64 + ks * 32 + lhi * 8) ^ (l7 << 3)];
#pragma unroll
      for (int dt = 0; dt < 4; ++dt) {
        const bf16x8 vf =
            *(const bf16x8*)&vtl[buf][(dt * 16 + l15) * 64 + ((ks * 4 + lhi) ^ l7) * 8];
        o[dt] = __builtin_amdgcn_mfma_f32_16x16x32_bf16(vf, pf, o[dt], 0, 0, 0);
      }
    }
    asm volatile("" ::: "memory");
    __syncthreads();
    buf ^= 1;
  }
#undef STAGE
  const float inv = 1.f / lsum;
  u16* crow = ctx + ((size_t)(b * 2048 + q0 + l15)) * 1024 + h * 64;
#pragma unroll
  for (int dt = 0; dt < 4; ++dt) {
    u16x4 ov;
#pragma unroll
    for (int r = 0; r < 4; ++r) ov[r] = f2bf(o[dt][r] * inv);
    *(u16x4*)&crow[dt * 16 + lhi * 4] = ov;
  }
}

extern "C" void kernel_launch(void* const* d_in, const int* in_sizes, int n_in,
                              void* d_out, int out_size, void* d_ws, size_t ws_size,
                              hipStream_t stream) {
  const float* x     = (const float*)d_in[0];
  const float* w_qkv = (const float*)d_in[1];
  const float* b_qkv = (const float*)d_in[2];
  const float* w_out = (const float*)d_in[3];
  const float* b_out = (const float*)d_in[4];
  const float* w1    = (const float*)d_in[5];
  const float* b1    = (const float*)d_in[6];
  const float* w2    = (const float*)d_in[7];
  const float* b2    = (const float*)d_in[8];
  const float* ln1g  = (const float*)d_in[9];
  const float* ln1b  = (const float*)d_in[10];
  const float* ln2g  = (const float*)d_in[11];
  const float* ln2b  = (const float*)d_in[12];
  float* out = (float*)d_out;

  u16* wqkv_b = (u16*)d_ws;                       // 3072*1024
  u16* wout_b = wqkv_b + (size_t)3072 * 1024;     // 1024*1024
  u16* w1_b   = wout_b + (size_t)1024 * 1024;     // 4096*1024
  u16* w2_b   = w1_b + (size_t)4096 * 1024;       // 1024*4096
  u16* r1     = w2_b + (size_t)1024 * 4096;       // 4096*1024: h1 / ctx / h2
  u16* r2     = r1 + (size_t)4096 * 1024;         // 4096*4096: qkv+vt, then hff
  u16* qkvb   = r2;
  u16* vtb    = r2 + (size_t)4096 * 3072;
  float* x2   = (float*)(r2 + (size_t)4096 * 4096); // 4096*1024 f32

  // weight conversion
  cvt_f32_bf16<<<1024, 256, 0, stream>>>(w_qkv, wqkv_b, 3072 * 1024 / 4);
  cvt_f32_bf16<<<1024, 256, 0, stream>>>(w_out, wout_b, 1024 * 1024 / 4);
  cvt_f32_bf16<<<1024, 256, 0, stream>>>(w1, w1_b, 4096 * 1024 / 4);
  cvt_f32_bf16<<<1024, 256, 0, stream>>>(w2, w2_b, 1024 * 4096 / 4);

  // LN1 -> h1 (r1)
  ln_k<<<4096, 256, 0, stream>>>(x, ln1g, ln1b, r1);
  // QKV GEMM: [4096,1024] x [3072,1024]^T -> qkv bf16 (256^2 tiles, 192 blk)
  gemm_rot<256, 256, 512, 4, 8, 4, 0><<<dim3(12, 16), 512, 0, stream>>>(
      r1, wqkv_b, b_qkv, nullptr, qkvb, 3072, 1024);
  // V transpose
  vtrans<<<dim3(32, 32), 256, 0, stream>>>(qkvb, vtb);
  // attention -> ctx (r1)
  attn_k<<<dim3(32, 32), 256, 0, stream>>>(qkvb, vtb, r1);
  // out-proj + residual -> x2 (f32) (128^2, 256 blk)
  gemm_rot<128, 128, 256, 2, 4, 4, 1><<<dim3(8, 32), 256, 0, stream>>>(
      r1, wout_b, b_out, x, x2, 1024, 1024);
  // LN2 -> h2 (r1)
  ln_k<<<4096, 256, 0, stream>>>(x2, ln2g, ln2b, r1);
  // MLP1 + ReLU -> hff (r2) (256^2, 256 blk)
  gemm_rot<256, 256, 512, 4, 8, 4, 2><<<dim3(16, 16), 512, 0, stream>>>(
      r1, w1_b, b1, nullptr, r2, 4096, 1024);
  // MLP2 + residual -> out (f32) (128^2, 256 blk, K=4096)
  gemm_rot<128, 128, 256, 2, 4, 4, 1><<<dim3(8, 32), 256, 0, stream>>>(
      r2, w2_b, b2, x2, out, 1024, 4096);
}

// Round 6
// 265.228 us; speedup vs baseline: 2.0856x; 1.0299x over previous
//
#include <hip/hip_runtime.h>
#include <hip/hip_bf16.h>

typedef __attribute__((ext_vector_type(8))) short bf16x8;
typedef __attribute__((ext_vector_type(4))) float f32x4;
typedef __attribute__((ext_vector_type(4))) unsigned short u16x4;
typedef unsigned short u16;

__device__ __forceinline__ u16 f2bf(float f) {
  unsigned u = __builtin_bit_cast(unsigned, f);
  u += 0x7fffu + ((u >> 16) & 1u);
  return (u16)(u >> 16);
}
__device__ __forceinline__ float bf2f(u16 u) {
  unsigned v = ((unsigned)u) << 16;
  return __builtin_bit_cast(float, v);
}
// packed f32x2 -> bf16x2 (RNE) via v_cvt_pk_bf16_f32 (no builtin on gfx950)
__device__ __forceinline__ unsigned cvt_pk_bf16(float lo, float hi) {
  unsigned r;
  asm("v_cvt_pk_bf16_f32 %0, %1, %2" : "=v"(r) : "v"(lo), "v"(hi));
  return r;
}

__device__ __forceinline__ void gl_lds16(const void* g, void* l) {
  __builtin_amdgcn_global_load_lds((const __attribute__((address_space(1))) void*)g,
                                   (__attribute__((address_space(3))) void*)l,
                                   16, 0, 0);
}

__device__ __forceinline__ void bar() {
  asm volatile("" ::: "memory");
  __builtin_amdgcn_s_barrier();
  asm volatile("" ::: "memory");
}

// ---------------- f32 -> bf16 convert ----------------
__global__ __launch_bounds__(256) void cvt_f32_bf16(const float* __restrict__ in,
                                                    u16* __restrict__ out, int n4) {
  int i = blockIdx.x * 256 + threadIdx.x;
  const int stride = gridDim.x * 256;
  for (; i < n4; i += stride) {
    float4 v = ((const float4*)in)[i];
    u16x4 o;
    o.x = f2bf(v.x); o.y = f2bf(v.y); o.z = f2bf(v.z); o.w = f2bf(v.w);
    ((u16x4*)out)[i] = o;
  }
}

// ---------------- LayerNorm: f32 in, bf16 out (D=1024) ----------------
__global__ __launch_bounds__(256) void ln_k(const float* __restrict__ x,
                                            const float* __restrict__ g,
                                            const float* __restrict__ b,
                                            u16* __restrict__ out) {
  const int row = blockIdx.x;
  const int t = threadIdx.x;
  const int lane = t & 63, w = t >> 6;
  const float4 v = ((const float4*)(x + (size_t)row * 1024))[t];
  float s = v.x + v.y + v.z + v.w;
  float q = v.x * v.x + v.y * v.y + v.z * v.z + v.w * v.w;
#pragma unroll
  for (int off = 32; off; off >>= 1) {
    s += __shfl_down(s, off);
    q += __shfl_down(q, off);
  }
  __shared__ float red[8];
  if (lane == 0) { red[w] = s; red[4 + w] = q; }
  __syncthreads();
  s = red[0] + red[1] + red[2] + red[3];
  q = red[4] + red[5] + red[6] + red[7];
  const float mu = s * (1.f / 1024.f);
  const float var = q * (1.f / 1024.f) - mu * mu;
  const float rs = rsqrtf(var + 1e-5f);
  const float4 gv = ((const float4*)g)[t];
  const float4 bv = ((const float4*)b)[t];
  u16x4 o;
  o.x = f2bf((v.x - mu) * rs * gv.x + bv.x);
  o.y = f2bf((v.y - mu) * rs * gv.y + bv.y);
  o.z = f2bf((v.z - mu) * rs * gv.z + bv.z);
  o.w = f2bf((v.w - mu) * rs * gv.w + bv.w);
  ((u16x4*)(out + (size_t)row * 1024))[t] = o;
}

// ---- NT GEMM, 3-buffer rotation, counted vmcnt, T2 swizzle, XCD swizzle ----
template <int BM, int BN, int TH, int WN, int MR, int NR, int EPI>
__global__ __launch_bounds__(TH, 2) void gemm_rot(const u16* __restrict__ A,
                                                  const u16* __restrict__ B,
                                                  const float* __restrict__ bias,
                                                  const float* __restrict__ res,
                                                  void* __restrict__ outp,
                                                  const int N, const int K) {
  constexpr int AELEMS = BM * 32;  // u16 elems per A tile (BK=32)
  constexpr int BELEMS = BN * 32;
  __shared__ u16 lds[3][AELEMS + BELEMS];
  const int t = threadIdx.x;
  const int lane = t & 63, w = t >> 6;
  const int wm = w / WN, wn = w % WN;
  const int l15 = lane & 15, lhi = lane >> 4;
  const int nbx = gridDim.x;
  const int nwg = nbx * gridDim.y;
  const int orig = blockIdx.y * nbx + blockIdx.x;
  const int cpx = nwg >> 3;
  const int lid = (orig & 7) * cpx + (orig >> 3);
  const long bm = (long)(lid / nbx) * BM, bn = (long)(lid % nbx) * BN;
  const u16* Ab = A + bm * K;
  const u16* Bb = B + bn * K;
  const int nk = K >> 5;

  const int s0 = t, s1 = TH + t;
  const int ar0 = s0 >> 2, ag0 = (s0 & 3) ^ ((ar0 >> 1) & 3);
  const int ar1 = s1 >> 2, ag1 = (s1 & 3) ^ ((ar1 >> 1) & 3);

#define STAGE(kt, bufi)                                                       \
  do {                                                                        \
    const long kk_ = (long)(kt) << 5;                                         \
    gl_lds16(Ab + (size_t)ar0 * K + kk_ + ag0 * 8, &lds[bufi][(size_t)(w * 64) * 8]);            \
    gl_lds16(Ab + (size_t)ar1 * K + kk_ + ag1 * 8, &lds[bufi][(size_t)(TH + w * 64) * 8]);       \
    gl_lds16(Bb + (size_t)ar0 * K + kk_ + ag0 * 8, &lds[bufi][AELEMS + (size_t)(w * 64) * 8]);   \
    gl_lds16(Bb + (size_t)ar1 * K + kk_ + ag1 * 8, &lds[bufi][AELEMS + (size_t)(TH + w * 64) * 8]); \
  } while (0)

  f32x4 acc[MR][NR] = {};
  STAGE(0, 0);
  STAGE(1, 1);
  STAGE(2, 2);
  for (int i = 0; i < nk; ++i) {
    if (i + 2 < nk)      asm volatile("s_waitcnt vmcnt(8)" ::: "memory");
    else if (i + 1 < nk) asm volatile("s_waitcnt vmcnt(4)" ::: "memory");
    else                 asm volatile("s_waitcnt vmcnt(0)" ::: "memory");
    bar();
    const u16* bufA = lds[i % 3];
    const u16* bufB = bufA + AELEMS;
    bf16x8 av[MR], bv[NR];
#pragma unroll
    for (int ii = 0; ii < MR; ++ii) {
      const int R = wm * (MR * 16) + ii * 16 + l15;
      av[ii] = *(const bf16x8*)&bufA[R * 32 + ((lhi ^ ((R >> 1) & 3)) << 3)];
    }
#pragma unroll
    for (int jj = 0; jj < NR; ++jj) {
      const int R = wn * (NR * 16) + jj * 16 + l15;
      bv[jj] = *(const bf16x8*)&bufB[R * 32 + ((lhi ^ ((R >> 1) & 3)) << 3)];
    }
    __builtin_amdgcn_s_setprio(1);
#pragma unroll
    for (int ii = 0; ii < MR; ++ii)
#pragma unroll
      for (int jj = 0; jj < NR; ++jj)
        acc[ii][jj] = __builtin_amdgcn_mfma_f32_16x16x32_bf16(av[ii], bv[jj], acc[ii][jj], 0, 0, 0);
    __builtin_amdgcn_s_setprio(0);
    bar();
    if (i + 3 < nk) STAGE(i + 3, i % 3);
  }
#undef STAGE
#pragma unroll
  for (int jj = 0; jj < NR; ++jj) {
    const long col = bn + wn * (NR * 16) + jj * 16 + l15;
    const float bj = bias[col];
#pragma unroll
    for (int ii = 0; ii < MR; ++ii) {
      const long row0 = bm + wm * (MR * 16) + ii * 16 + lhi * 4;
#pragma unroll
      for (int r = 0; r < 4; ++r) {
        const float v = acc[ii][jj][r] + bj;
        const long idx = (row0 + r) * N + col;
        if constexpr (EPI == 0) {
          ((u16*)outp)[idx] = f2bf(v);
        } else if constexpr (EPI == 1) {
          ((float*)outp)[idx] = v + res[idx];
        } else {
          ((u16*)outp)[idx] = f2bf(v > 0.f ? v : 0.f);
        }
      }
    }
  }
}

// ---------------- V transpose: qkv -> vt[bh][d][kv] ----------------
__global__ __launch_bounds__(256) void vtrans(const u16* __restrict__ qkv,
                                              u16* __restrict__ vt) {
  const int t = threadIdx.x;
  const int bh = blockIdx.y, b = bh >> 4, h = bh & 15;
  const int kvb = blockIdx.x * 64;
  __shared__ u16 tile[64][72];
  const u16* src = qkv + ((size_t)(b * 2048 + kvb)) * 3072 + h * 192 + 128;
#pragma unroll
  for (int rr = 0; rr < 2; ++rr) {
    const int e = rr * 2048 + t * 8;
    const int kv = e >> 6, d = e & 63;
    *(bf16x8*)&tile[kv][d] = *(const bf16x8*)(src + (size_t)kv * 3072 + d);
  }
  __syncthreads();
#pragma unroll
  for (int rr = 0; rr < 2; ++rr) {
    const int e = rr * 2048 + t * 8;
    const int d = e >> 6, kv = e & 63;
    bf16x8 o;
#pragma unroll
    for (int j = 0; j < 8; ++j) o[j] = (short)tile[kv + j][d];
    *(bf16x8*)(vt + ((size_t)bh * 64 + d) * 2048 + kvb + kv) = o;
  }
}

// ---------------- Flash attention (counted-vmcnt pipeline, cvt_pk pack) ---
// grid (S/64, B*H), 4 waves, each wave owns 16 q rows; KV tiles of 64.
// QK^T as mfma(K,Q): lane holds S[q=l15][kv=jt*16+lhi*4+r]; lane-local softmax.
// PV as mfma(Vt,P); defer-max THR=8 (log2 space).
__global__ __launch_bounds__(256, 4) void attn_k(const u16* __restrict__ qkv,
                                                 const u16* __restrict__ vt,
                                                 u16* __restrict__ ctx) {
  __shared__ u16 kt[2][4096];
  __shared__ u16 vtl[2][4096];
  __shared__ u16 plds[4][1024];
  const int t = threadIdx.x;
  const int lane = t & 63, w = t >> 6;
  const int l15 = lane & 15, lhi = lane >> 4;
  const int l7 = l15 & 7;
  const int bh = blockIdx.y, b = bh >> 4, h = bh & 15;
  const int q0 = blockIdx.x * 64 + w * 16;

  const float qscale = 0.125f * 1.44269504f;
  const u16* qp = qkv + ((size_t)(b * 2048 + q0 + l15)) * 3072 + h * 192 + lhi * 8;
  bf16x8 qf0 = *(const bf16x8*)qp;
  bf16x8 qf1 = *(const bf16x8*)(qp + 32);
#pragma unroll
  for (int j = 0; j < 8; ++j) {
    qf0[j] = (short)f2bf(bf2f((u16)qf0[j]) * qscale);
    qf1[j] = (short)f2bf(bf2f((u16)qf1[j]) * qscale);
  }

  const int srow = t >> 3, sgc = t & 7;
  const int sswz = (sgc ^ (srow & 7)) * 8;
  const u16* kg0 = qkv + ((size_t)(b * 2048 + srow)) * 3072 + h * 192 + 64 + sswz;
  const u16* vg0 = vt + (size_t)bh * 64 * 2048 + (size_t)srow * 2048 + sswz;
  u16* plds_w = &plds[w][0];

  f32x4 o[4] = {};
  float m = -1e30f, lsum = 0.f;

#define STAGE(bufi, kv0i)                                              \
  do {                                                                 \
    const u16* ks_ = kg0 + (size_t)(kv0i) * 3072;                      \
    const u16* vs_ = vg0 + (kv0i);                                     \
    gl_lds16(ks_, &kt[bufi][w * 512]);                                 \
    gl_lds16(ks_ + (size_t)32 * 3072, &kt[bufi][2048 + w * 512]);      \
    gl_lds16(vs_, &vtl[bufi][w * 512]);                                \
    gl_lds16(vs_ + (size_t)32 * 2048, &vtl[bufi][2048 + w * 512]);     \
  } while (0)

  int buf = 0;
  STAGE(0, 0);
  for (int kv0 = 0; kv0 < 2048; kv0 += 64) {
    // issue next tile, keep it in flight across the barrier (counted vmcnt)
    if (kv0 + 64 < 2048) {
      STAGE(buf ^ 1, kv0 + 64);
      asm volatile("s_waitcnt vmcnt(4)" ::: "memory");
    } else {
      asm volatile("s_waitcnt vmcnt(0)" ::: "memory");
    }
    bar();
    // ---- QK^T swapped: s[jt][r] = S[q=l15][kv=jt*16+lhi*4+r] ----
    f32x4 s[4];
    __builtin_amdgcn_s_setprio(1);
#pragma unroll
    for (int jt = 0; jt < 4; ++jt) {
      const int krow = (jt * 16 + l15) * 64;
      const bf16x8 k0 = *(const bf16x8*)&kt[buf][krow + ((0 * 4 + lhi) ^ l7) * 8];
      const bf16x8 k1 = *(const bf16x8*)&kt[buf][krow + ((1 * 4 + lhi) ^ l7) * 8];
      f32x4 z = {};
      z = __builtin_amdgcn_mfma_f32_16x16x32_bf16(k0, qf0, z, 0, 0, 0);
      s[jt] = __builtin_amdgcn_mfma_f32_16x16x32_bf16(k1, qf1, z, 0, 0, 0);
    }
    __builtin_amdgcn_s_setprio(0);
    // ---- lane-local online softmax (exp2 space) ----
    float px0 = fmaxf(fmaxf(s[0][0], s[0][1]), fmaxf(s[0][2], s[0][3]));
    float px1 = fmaxf(fmaxf(s[1][0], s[1][1]), fmaxf(s[1][2], s[1][3]));
    float px2 = fmaxf(fmaxf(s[2][0], s[2][1]), fmaxf(s[2][2], s[2][3]));
    float px3 = fmaxf(fmaxf(s[3][0], s[3][1]), fmaxf(s[3][2], s[3][3]));
    float pmax = fmaxf(fmaxf(px0, px1), fmaxf(px2, px3));
    pmax = fmaxf(pmax, __shfl_xor(pmax, 16));
    pmax = fmaxf(pmax, __shfl_xor(pmax, 32));
    if (!__all(pmax <= m + 8.f)) {
      const float mn = fmaxf(m, pmax);
      const float sc = exp2f(m - mn);
      m = mn;
      lsum *= sc;
#pragma unroll
      for (int dt = 0; dt < 4; ++dt)
#pragma unroll
        for (int r = 0; r < 4; ++r) o[dt][r] *= sc;
    }
    float rsum = 0.f;
    uint2 pw[4];
#pragma unroll
    for (int jt = 0; jt < 4; ++jt) {
      const float p0 = exp2f(s[jt][0] - m);
      const float p1 = exp2f(s[jt][1] - m);
      const float p2 = exp2f(s[jt][2] - m);
      const float p3 = exp2f(s[jt][3] - m);
      rsum += (p0 + p1) + (p2 + p3);
      pw[jt].x = cvt_pk_bf16(p0, p1);
      pw[jt].y = cvt_pk_bf16(p2, p3);
    }
    rsum += __shfl_xor(rsum, 16);
    rsum += __shfl_xor(rsum, 32);
    lsum += rsum;
    // ---- P -> LDS (packed b64 writes, swizzled) ----
#pragma unroll
    for (int jt = 0; jt < 4; ++jt)
      *(uint2*)&plds_w[(l15 * 64 + jt * 16 + lhi * 4) ^ (l7 << 3)] = pw[jt];
    asm volatile("" ::: "memory");
    // ---- PV swapped: o[dt][r] = O[q=l15][d=dt*16+lhi*4+r] ----
    __builtin_amdgcn_s_setprio(1);
#pragma unroll
    for (int ks = 0; ks < 2; ++ks) {
      const bf16x8 pf =
          *(const bf16x8*)&plds_w[(l15 * 64 + ks * 32 + lhi * 8) ^ (l7 << 3)];
#pragma unroll
      for (int dt = 0; dt < 4; ++dt) {
        const bf16x8 vf =
            *(const bf16x8*)&vtl[buf][(dt * 16 + l15) * 64 + ((ks * 4 + lhi) ^ l7) * 8];
        o[dt] = __builtin_amdgcn_mfma_f32_16x16x32_bf16(vf, pf, o[dt], 0, 0, 0);
      }
    }
    __builtin_amdgcn_s_setprio(0);
    asm volatile("" ::: "memory");
    bar();
    buf ^= 1;
  }
#undef STAGE
  const float inv = 1.f / lsum;
  u16* crow = ctx + ((size_t)(b * 2048 + q0 + l15)) * 1024 + h * 64;
#pragma unroll
  for (int dt = 0; dt < 4; ++dt) {
    uint2 ov;
    ov.x = cvt_pk_bf16(o[dt][0] * inv, o[dt][1] * inv);
    ov.y = cvt_pk_bf16(o[dt][2] * inv, o[dt][3] * inv);
    *(uint2*)&crow[dt * 16 + lhi * 4] = ov;
  }
}

extern "C" void kernel_launch(void* const* d_in, const int* in_sizes, int n_in,
                              void* d_out, int out_size, void* d_ws, size_t ws_size,
                              hipStream_t stream) {
  const float* x     = (const float*)d_in[0];
  const float* w_qkv = (const float*)d_in[1];
  const float* b_qkv = (const float*)d_in[2];
  const float* w_out = (const float*)d_in[3];
  const float* b_out = (const float*)d_in[4];
  const float* w1    = (const float*)d_in[5];
  const float* b1    = (const float*)d_in[6];
  const float* w2    = (const float*)d_in[7];
  const float* b2    = (const float*)d_in[8];
  const float* ln1g  = (const float*)d_in[9];
  const float* ln1b  = (const float*)d_in[10];
  const float* ln2g  = (const float*)d_in[11];
  const float* ln2b  = (const float*)d_in[12];
  float* out = (float*)d_out;

  u16* wqkv_b = (u16*)d_ws;                       // 3072*1024
  u16* wout_b = wqkv_b + (size_t)3072 * 1024;     // 1024*1024
  u16* w1_b   = wout_b + (size_t)1024 * 1024;     // 4096*1024
  u16* w2_b   = w1_b + (size_t)4096 * 1024;       // 1024*4096
  u16* r1     = w2_b + (size_t)1024 * 4096;       // 4096*1024: h1 / ctx / h2
  u16* r2     = r1 + (size_t)4096 * 1024;         // 4096*4096: qkv+vt, then hff
  u16* qkvb   = r2;
  u16* vtb    = r2 + (size_t)4096 * 3072;
  float* x2   = (float*)(r2 + (size_t)4096 * 4096); // 4096*1024 f32

  // weight conversion
  cvt_f32_bf16<<<1024, 256, 0, stream>>>(w_qkv, wqkv_b, 3072 * 1024 / 4);
  cvt_f32_bf16<<<1024, 256, 0, stream>>>(w_out, wout_b, 1024 * 1024 / 4);
  cvt_f32_bf16<<<1024, 256, 0, stream>>>(w1, w1_b, 4096 * 1024 / 4);
  cvt_f32_bf16<<<1024, 256, 0, stream>>>(w2, w2_b, 1024 * 4096 / 4);

  // LN1 -> h1 (r1)
  ln_k<<<4096, 256, 0, stream>>>(x, ln1g, ln1b, r1);
  // QKV GEMM: [4096,1024] x [3072,1024]^T -> qkv bf16 (256^2 tiles)
  gemm_rot<256, 256, 512, 4, 8, 4, 0><<<dim3(12, 16), 512, 0, stream>>>(
      r1, wqkv_b, b_qkv, nullptr, qkvb, 3072, 1024);
  // V transpose
  vtrans<<<dim3(32, 32), 256, 0, stream>>>(qkvb, vtb);
  // attention -> ctx (r1)
  attn_k<<<dim3(32, 32), 256, 0, stream>>>(qkvb, vtb, r1);
  // out-proj + residual -> x2 (f32) (128^2)
  gemm_rot<128, 128, 256, 2, 4, 4, 1><<<dim3(8, 32), 256, 0, stream>>>(
      r1, wout_b, b_out, x, x2, 1024, 1024);
  // LN2 -> h2 (r1)
  ln_k<<<4096, 256, 0, stream>>>(x2, ln2g, ln2b, r1);
  // MLP1 + ReLU -> hff (r2) (256^2)
  gemm_rot<256, 256, 512, 4, 8, 4, 2><<<dim3(16, 16), 512, 0, stream>>>(
      r1, w1_b, b1, nullptr, r2, 4096, 1024);
  // MLP2 + residual -> out (f32) (128^2, K=4096)
  gemm_rot<128, 128, 256, 2, 4, 4, 1><<<dim3(8, 32), 256, 0, stream>>>(
      r2, w2_b, b2, x2, out, 1024, 4096);
}

// Round 7
// 261.545 us; speedup vs baseline: 2.1150x; 1.0141x over previous
//
#include <hip/hip_runtime.h>
#include <hip/hip_bf16.h>

typedef __attribute__((ext_vector_type(8))) short bf16x8;
typedef __attribute__((ext_vector_type(4))) float f32x4;
typedef __attribute__((ext_vector_type(16))) float f32x16;
typedef __attribute__((ext_vector_type(4))) unsigned short u16x4;
typedef __attribute__((ext_vector_type(4))) unsigned int u32x4;
typedef unsigned short u16;

__device__ __forceinline__ u16 f2bf(float f) {
  unsigned u = __builtin_bit_cast(unsigned, f);
  u += 0x7fffu + ((u >> 16) & 1u);
  return (u16)(u >> 16);
}
__device__ __forceinline__ float bf2f(u16 u) {
  unsigned v = ((unsigned)u) << 16;
  return __builtin_bit_cast(float, v);
}
// packed f32x2 -> bf16x2 (RNE) via v_cvt_pk_bf16_f32 (no builtin on gfx950)
__device__ __forceinline__ unsigned cvt_pk_bf16(float lo, float hi) {
  unsigned r;
  asm("v_cvt_pk_bf16_f32 %0, %1, %2" : "=v"(r) : "v"(lo), "v"(hi));
  return r;
}

__device__ __forceinline__ void gl_lds16(const void* g, void* l) {
  __builtin_amdgcn_global_load_lds((const __attribute__((address_space(1))) void*)g,
                                   (__attribute__((address_space(3))) void*)l,
                                   16, 0, 0);
}

__device__ __forceinline__ void bar() {
  asm volatile("" ::: "memory");
  __builtin_amdgcn_s_barrier();
  asm volatile("" ::: "memory");
}

// ---------------- f32 -> bf16 convert ----------------
__global__ __launch_bounds__(256) void cvt_f32_bf16(const float* __restrict__ in,
                                                    u16* __restrict__ out, int n4) {
  int i = blockIdx.x * 256 + threadIdx.x;
  const int stride = gridDim.x * 256;
  for (; i < n4; i += stride) {
    float4 v = ((const float4*)in)[i];
    u16x4 o;
    o.x = f2bf(v.x); o.y = f2bf(v.y); o.z = f2bf(v.z); o.w = f2bf(v.w);
    ((u16x4*)out)[i] = o;
  }
}

// ---------------- LayerNorm: f32 in, bf16 out (D=1024) ----------------
__global__ __launch_bounds__(256) void ln_k(const float* __restrict__ x,
                                            const float* __restrict__ g,
                                            const float* __restrict__ b,
                                            u16* __restrict__ out) {
  const int row = blockIdx.x;
  const int t = threadIdx.x;
  const int lane = t & 63, w = t >> 6;
  const float4 v = ((const float4*)(x + (size_t)row * 1024))[t];
  float s = v.x + v.y + v.z + v.w;
  float q = v.x * v.x + v.y * v.y + v.z * v.z + v.w * v.w;
#pragma unroll
  for (int off = 32; off; off >>= 1) {
    s += __shfl_down(s, off);
    q += __shfl_down(q, off);
  }
  __shared__ float red[8];
  if (lane == 0) { red[w] = s; red[4 + w] = q; }
  __syncthreads();
  s = red[0] + red[1] + red[2] + red[3];
  q = red[4] + red[5] + red[6] + red[7];
  const float mu = s * (1.f / 1024.f);
  const float var = q * (1.f / 1024.f) - mu * mu;
  const float rs = rsqrtf(var + 1e-5f);
  const float4 gv = ((const float4*)g)[t];
  const float4 bv = ((const float4*)b)[t];
  u16x4 o;
  o.x = f2bf((v.x - mu) * rs * gv.x + bv.x);
  o.y = f2bf((v.y - mu) * rs * gv.y + bv.y);
  o.z = f2bf((v.z - mu) * rs * gv.z + bv.z);
  o.w = f2bf((v.w - mu) * rs * gv.w + bv.w);
  ((u16x4*)(out + (size_t)row * 1024))[t] = o;
}

// ---- NT GEMM, 3-buffer rotation, counted vmcnt, T2 swizzle, XCD swizzle ----
template <int BM, int BN, int TH, int WN, int MR, int NR, int EPI>
__global__ __launch_bounds__(TH, 2) void gemm_rot(const u16* __restrict__ A,
                                                  const u16* __restrict__ B,
                                                  const float* __restrict__ bias,
                                                  const float* __restrict__ res,
                                                  void* __restrict__ outp,
                                                  const int N, const int K) {
  constexpr int AELEMS = BM * 32;  // u16 elems per A tile (BK=32)
  constexpr int BELEMS = BN * 32;
  __shared__ u16 lds[3][AELEMS + BELEMS];
  const int t = threadIdx.x;
  const int lane = t & 63, w = t >> 6;
  const int wm = w / WN, wn = w % WN;
  const int l15 = lane & 15, lhi = lane >> 4;
  const int nbx = gridDim.x;
  const int nwg = nbx * gridDim.y;
  const int orig = blockIdx.y * nbx + blockIdx.x;
  const int cpx = nwg >> 3;
  const int lid = (orig & 7) * cpx + (orig >> 3);
  const long bm = (long)(lid / nbx) * BM, bn = (long)(lid % nbx) * BN;
  const u16* Ab = A + bm * K;
  const u16* Bb = B + bn * K;
  const int nk = K >> 5;

  const int s0 = t, s1 = TH + t;
  const int ar0 = s0 >> 2, ag0 = (s0 & 3) ^ ((ar0 >> 1) & 3);
  const int ar1 = s1 >> 2, ag1 = (s1 & 3) ^ ((ar1 >> 1) & 3);

#define STAGE(kt, bufi)                                                       \
  do {                                                                        \
    const long kk_ = (long)(kt) << 5;                                         \
    gl_lds16(Ab + (size_t)ar0 * K + kk_ + ag0 * 8, &lds[bufi][(size_t)(w * 64) * 8]);            \
    gl_lds16(Ab + (size_t)ar1 * K + kk_ + ag1 * 8, &lds[bufi][(size_t)(TH + w * 64) * 8]);       \
    gl_lds16(Bb + (size_t)ar0 * K + kk_ + ag0 * 8, &lds[bufi][AELEMS + (size_t)(w * 64) * 8]);   \
    gl_lds16(Bb + (size_t)ar1 * K + kk_ + ag1 * 8, &lds[bufi][AELEMS + (size_t)(TH + w * 64) * 8]); \
  } while (0)

  f32x4 acc[MR][NR] = {};
  STAGE(0, 0);
  STAGE(1, 1);
  STAGE(2, 2);
  for (int i = 0; i < nk; ++i) {
    if (i + 2 < nk)      asm volatile("s_waitcnt vmcnt(8)" ::: "memory");
    else if (i + 1 < nk) asm volatile("s_waitcnt vmcnt(4)" ::: "memory");
    else                 asm volatile("s_waitcnt vmcnt(0)" ::: "memory");
    bar();
    const u16* bufA = lds[i % 3];
    const u16* bufB = bufA + AELEMS;
    bf16x8 av[MR], bv[NR];
#pragma unroll
    for (int ii = 0; ii < MR; ++ii) {
      const int R = wm * (MR * 16) + ii * 16 + l15;
      av[ii] = *(const bf16x8*)&bufA[R * 32 + ((lhi ^ ((R >> 1) & 3)) << 3)];
    }
#pragma unroll
    for (int jj = 0; jj < NR; ++jj) {
      const int R = wn * (NR * 16) + jj * 16 + l15;
      bv[jj] = *(const bf16x8*)&bufB[R * 32 + ((lhi ^ ((R >> 1) & 3)) << 3)];
    }
    __builtin_amdgcn_s_setprio(1);
#pragma unroll
    for (int ii = 0; ii < MR; ++ii)
#pragma unroll
      for (int jj = 0; jj < NR; ++jj)
        acc[ii][jj] = __builtin_amdgcn_mfma_f32_16x16x32_bf16(av[ii], bv[jj], acc[ii][jj], 0, 0, 0);
    __builtin_amdgcn_s_setprio(0);
    bar();
    if (i + 3 < nk) STAGE(i + 3, i % 3);
  }
#undef STAGE
#pragma unroll
  for (int jj = 0; jj < NR; ++jj) {
    const long col = bn + wn * (NR * 16) + jj * 16 + l15;
    const float bj = bias[col];
#pragma unroll
    for (int ii = 0; ii < MR; ++ii) {
      const long row0 = bm + wm * (MR * 16) + ii * 16 + lhi * 4;
#pragma unroll
      for (int r = 0; r < 4; ++r) {
        const float v = acc[ii][jj][r] + bj;
        const long idx = (row0 + r) * N + col;
        if constexpr (EPI == 0) {
          ((u16*)outp)[idx] = f2bf(v);
        } else if constexpr (EPI == 1) {
          ((float*)outp)[idx] = v + res[idx];
        } else {
          ((u16*)outp)[idx] = f2bf(v > 0.f ? v : 0.f);
        }
      }
    }
  }
}

// ---------------- V transpose: qkv -> vt[bh][d][kv] ----------------
__global__ __launch_bounds__(256) void vtrans(const u16* __restrict__ qkv,
                                              u16* __restrict__ vt) {
  const int t = threadIdx.x;
  const int bh = blockIdx.y, b = bh >> 4, h = bh & 15;
  const int kvb = blockIdx.x * 64;
  __shared__ u16 tile[64][72];
  const u16* src = qkv + ((size_t)(b * 2048 + kvb)) * 3072 + h * 192 + 128;
#pragma unroll
  for (int rr = 0; rr < 2; ++rr) {
    const int e = rr * 2048 + t * 8;
    const int kv = e >> 6, d = e & 63;
    *(bf16x8*)&tile[kv][d] = *(const bf16x8*)(src + (size_t)kv * 3072 + d);
  }
  __syncthreads();
#pragma unroll
  for (int rr = 0; rr < 2; ++rr) {
    const int e = rr * 2048 + t * 8;
    const int d = e >> 6, kv = e & 63;
    bf16x8 o;
#pragma unroll
    for (int j = 0; j < 8; ++j) o[j] = (short)tile[kv + j][d];
    *(bf16x8*)(vt + ((size_t)bh * 64 + d) * 2048 + kvb + kv) = o;
  }
}

// ---------------- Flash attention, 32x32x16 MFMA, in-register P ----------
// grid (S/128, B*H), 4 waves; wave owns 32 q rows. KV tiles of 64, dbuf.
// QK^T swapped mfma(K,Q): S col=q=l&31 lane-local; 32 scores/lane (2 acc).
// P built in-register: cvt_pk pairs + v_permlane32_swap (lo lanes hold
// kv{0-3,8-11,..}, hi lanes kv{4-7,12-15,..}; swap exchanges the halves).
// PV swapped mfma(Vt,P). Epilogue: per-wave LDS transpose -> b128 stores.
__global__ __launch_bounds__(256, 2) void attn_k(const u16* __restrict__ qkv,
                                                 const u16* __restrict__ vt,
                                                 u16* __restrict__ ctx) {
  __shared__ u16 kt[2][4096];
  __shared__ u16 vtl[2][4096];
  __shared__ u16 olds[4][2048];
  const int t = threadIdx.x;
  const int lane = t & 63, w = t >> 6;
  const int l31 = lane & 31, hl = lane >> 5;
  const int l7 = l31 & 7;
  const int bh = blockIdx.y, b = bh >> 4, h = bh & 15;
  const int qb = blockIdx.x * 128 + w * 32;

  // Q fragments (B-operand of 32x32x16: col q = l31, k = d = 16*ds + 8*hl + j)
  const float qscale = 0.125f * 1.44269504f;
  const u16* qp = qkv + ((size_t)(b * 2048 + qb + l31)) * 3072 + h * 192;
  bf16x8 qf[4];
#pragma unroll
  for (int ds = 0; ds < 4; ++ds) {
    bf16x8 v = *(const bf16x8*)(qp + 16 * ds + 8 * hl);
#pragma unroll
    for (int j = 0; j < 8; ++j) v[j] = (short)f2bf(bf2f((u16)v[j]) * qscale);
    qf[ds] = v;
  }

  // staging: thread t covers (row = t>>3 [+32 on 2nd call], 16B-group = t&7)
  const int srow = t >> 3, sgc = t & 7;
  const int sswz = (sgc ^ (srow & 7)) * 8;
  const u16* kg0 = qkv + ((size_t)(b * 2048 + srow)) * 3072 + h * 192 + 64 + sswz;
  const u16* vg0 = vt + (size_t)bh * 64 * 2048 + (size_t)srow * 2048 + sswz;

  f32x16 o0 = {}, o1 = {};
  float m = -1e30f, lsum = 0.f;

#define STAGE(bufi, kv0i)                                              \
  do {                                                                 \
    const u16* ks_ = kg0 + (size_t)(kv0i) * 3072;                      \
    const u16* vs_ = vg0 + (kv0i);                                     \
    gl_lds16(ks_, &kt[bufi][w * 512]);                                 \
    gl_lds16(ks_ + (size_t)32 * 3072, &kt[bufi][2048 + w * 512]);      \
    gl_lds16(vs_, &vtl[bufi][w * 512]);                                \
    gl_lds16(vs_ + (size_t)32 * 2048, &vtl[bufi][2048 + w * 512]);     \
  } while (0)

#define PACK(dst, SA, tl)                                                 \
  do {                                                                    \
    unsigned A0 = cvt_pk_bf16(SA[8 * tl + 0], SA[8 * tl + 1]);            \
    unsigned A1 = cvt_pk_bf16(SA[8 * tl + 2], SA[8 * tl + 3]);            \
    unsigned B0 = cvt_pk_bf16(SA[8 * tl + 4], SA[8 * tl + 5]);            \
    unsigned B1 = cvt_pk_bf16(SA[8 * tl + 6], SA[8 * tl + 7]);            \
    asm volatile("v_permlane32_swap_b32 %0, %1" : "+v"(A0), "+v"(B0));    \
    asm volatile("v_permlane32_swap_b32 %0, %1" : "+v"(A1), "+v"(B1));    \
    u32x4 pv_ = {A0, A1, B0, B1};                                         \
    dst = __builtin_bit_cast(bf16x8, pv_);                                \
  } while (0)

  int buf = 0;
  STAGE(0, 0);
  for (int kv0 = 0; kv0 < 2048; kv0 += 64) {
    if (kv0 + 64 < 2048) {
      STAGE(buf ^ 1, kv0 + 64);
      asm volatile("s_waitcnt vmcnt(4)" ::: "memory");
    } else {
      asm volatile("s_waitcnt vmcnt(0)" ::: "memory");
    }
    bar();
    // ---- QK^T: sa0 = S[kv 0..31][q], sa1 = S[kv 32..63][q] ----
    f32x16 sa0 = {}, sa1 = {};
    __builtin_amdgcn_s_setprio(1);
#pragma unroll
    for (int ds = 0; ds < 4; ++ds) {
      const bf16x8 kf0 = *(const bf16x8*)&kt[buf][l31 * 64 + (((2 * ds + hl) ^ l7) << 3)];
      const bf16x8 kf1 = *(const bf16x8*)&kt[buf][(32 + l31) * 64 + (((2 * ds + hl) ^ l7) << 3)];
      sa0 = __builtin_amdgcn_mfma_f32_32x32x16_bf16(kf0, qf[ds], sa0, 0, 0, 0);
      sa1 = __builtin_amdgcn_mfma_f32_32x32x16_bf16(kf1, qf[ds], sa1, 0, 0, 0);
    }
    __builtin_amdgcn_s_setprio(0);
    // ---- lane-local online softmax (exp2 space), defer-max THR=8 ----
    float mx[16];
#pragma unroll
    for (int i = 0; i < 16; ++i) mx[i] = fmaxf(sa0[i], sa1[i]);
#pragma unroll
    for (int st = 8; st; st >>= 1)
#pragma unroll
      for (int i = 0; i < st; ++i) mx[i] = fmaxf(mx[i], mx[i + st]);
    float pmax = fmaxf(mx[0], __shfl_xor(mx[0], 32));
    if (!__all(pmax <= m + 8.f)) {
      const float mn = fmaxf(m, pmax);
      const float sc = exp2f(m - mn);
      m = mn;
      lsum *= sc;
      o0 *= sc;
      o1 *= sc;
    }
#pragma unroll
    for (int i = 0; i < 16; ++i) sa0[i] = exp2f(sa0[i] - m);
#pragma unroll
    for (int i = 0; i < 16; ++i) sa1[i] = exp2f(sa1[i] - m);
    float sm[16];
#pragma unroll
    for (int i = 0; i < 16; ++i) sm[i] = sa0[i] + sa1[i];
#pragma unroll
    for (int st = 8; st; st >>= 1)
#pragma unroll
      for (int i = 0; i < st; ++i) sm[i] += sm[i + st];
    lsum += sm[0] + __shfl_xor(sm[0], 32);
    // ---- pack P into B-fragments (in-register, permlane swap) ----
    bf16x8 pf0, pf1, pf2, pf3;
    PACK(pf0, sa0, 0);
    PACK(pf1, sa0, 1);
    PACK(pf2, sa1, 0);
    PACK(pf3, sa1, 1);
    // ---- PV: o0 = O[d 0..31][q], o1 = O[d 32..63][q] ----
    __builtin_amdgcn_s_setprio(1);
#pragma unroll
    for (int t4 = 0; t4 < 4; ++t4) {
      const bf16x8 vf0 = *(const bf16x8*)&vtl[buf][l31 * 64 + (((2 * t4 + hl) ^ l7) << 3)];
      const bf16x8 vf1 = *(const bf16x8*)&vtl[buf][(32 + l31) * 64 + (((2 * t4 + hl) ^ l7) << 3)];
      const bf16x8 pf = (t4 == 0) ? pf0 : (t4 == 1) ? pf1 : (t4 == 2) ? pf2 : pf3;
      o0 = __builtin_amdgcn_mfma_f32_32x32x16_bf16(vf0, pf, o0, 0, 0, 0);
      o1 = __builtin_amdgcn_mfma_f32_32x32x16_bf16(vf1, pf, o1, 0, 0, 0);
    }
    __builtin_amdgcn_s_setprio(0);
    bar();
    buf ^= 1;
  }
#undef STAGE
#undef PACK
  // ---- epilogue: per-wave transpose via LDS (swizzled), coalesced store ----
  const float inv = 1.f / lsum;
  u16* ow = &olds[w][0];
#pragma unroll
  for (int g2 = 0; g2 < 4; ++g2) {
    uint2 v0, v1;
    v0.x = cvt_pk_bf16(o0[4 * g2 + 0] * inv, o0[4 * g2 + 1] * inv);
    v0.y = cvt_pk_bf16(o0[4 * g2 + 2] * inv, o0[4 * g2 + 3] * inv);
    v1.x = cvt_pk_bf16(o1[4 * g2 + 0] * inv, o1[4 * g2 + 1] * inv);
    v1.y = cvt_pk_bf16(o1[4 * g2 + 2] * inv, o1[4 * g2 + 3] * inv);
    // d-group g16 = 4*dt + g2 stored at position g16 ^ (q&7); q = l31
    *(uint2*)&ow[l31 * 64 + ((g2 ^ l7) << 3) + hl * 4] = v0;
    *(uint2*)&ow[l31 * 64 + (((4 + g2) ^ l7) << 3) + hl * 4] = v1;
  }
  // same-wave read-after-write on olds: compiler orders via lgkmcnt
#pragma unroll
  for (int p = 0; p < 4; ++p) {
    const int q = 8 * p + (lane >> 3);
    const int gpos = lane & 7;
    const bf16x8 val = *(const bf16x8*)&ow[q * 64 + (gpos << 3)];
    const int gd = gpos ^ (q & 7);
    *(bf16x8*)(ctx + ((size_t)(b * 2048 + qb - w * 32 + w * 32 + q)) * 1024 + h * 64 + gd * 8) = val;
  }
}

extern "C" void kernel_launch(void* const* d_in, const int* in_sizes, int n_in,
                              void* d_out, int out_size, void* d_ws, size_t ws_size,
                              hipStream_t stream) {
  const float* x     = (const float*)d_in[0];
  const float* w_qkv = (const float*)d_in[1];
  const float* b_qkv = (const float*)d_in[2];
  const float* w_out = (const float*)d_in[3];
  const float* b_out = (const float*)d_in[4];
  const float* w1    = (const float*)d_in[5];
  const float* b1    = (const float*)d_in[6];
  const float* w2    = (const float*)d_in[7];
  const float* b2    = (const float*)d_in[8];
  const float* ln1g  = (const float*)d_in[9];
  const float* ln1b  = (const float*)d_in[10];
  const float* ln2g  = (const float*)d_in[11];
  const float* ln2b  = (const float*)d_in[12];
  float* out = (float*)d_out;

  u16* wqkv_b = (u16*)d_ws;                       // 3072*1024
  u16* wout_b = wqkv_b + (size_t)3072 * 1024;     // 1024*1024
  u16* w1_b   = wout_b + (size_t)1024 * 1024;     // 4096*1024
  u16* w2_b   = w1_b + (size_t)4096 * 1024;       // 1024*4096
  u16* r1     = w2_b + (size_t)1024 * 4096;       // 4096*1024: h1 / ctx / h2
  u16* r2     = r1 + (size_t)4096 * 1024;         // 4096*4096: qkv+vt, then hff
  u16* qkvb   = r2;
  u16* vtb    = r2 + (size_t)4096 * 3072;
  float* x2   = (float*)(r2 + (size_t)4096 * 4096); // 4096*1024 f32

  // weight conversion
  cvt_f32_bf16<<<1024, 256, 0, stream>>>(w_qkv, wqkv_b, 3072 * 1024 / 4);
  cvt_f32_bf16<<<1024, 256, 0, stream>>>(w_out, wout_b, 1024 * 1024 / 4);
  cvt_f32_bf16<<<1024, 256, 0, stream>>>(w1, w1_b, 4096 * 1024 / 4);
  cvt_f32_bf16<<<1024, 256, 0, stream>>>(w2, w2_b, 1024 * 4096 / 4);

  // LN1 -> h1 (r1)
  ln_k<<<4096, 256, 0, stream>>>(x, ln1g, ln1b, r1);
  // QKV GEMM: [4096,1024] x [3072,1024]^T -> qkv bf16 (256^2 tiles)
  gemm_rot<256, 256, 512, 4, 8, 4, 0><<<dim3(12, 16), 512, 0, stream>>>(
      r1, wqkv_b, b_qkv, nullptr, qkvb, 3072, 1024);
  // V transpose
  vtrans<<<dim3(32, 32), 256, 0, stream>>>(qkvb, vtb);
  // attention -> ctx (r1)
  attn_k<<<dim3(16, 32), 256, 0, stream>>>(qkvb, vtb, r1);
  // out-proj + residual -> x2 (f32) (128^2)
  gemm_rot<128, 128, 256, 2, 4, 4, 1><<<dim3(8, 32), 256, 0, stream>>>(
      r1, wout_b, b_out, x, x2, 1024, 1024);
  // LN2 -> h2 (r1)
  ln_k<<<4096, 256, 0, stream>>>(x2, ln2g, ln2b, r1);
  // MLP1 + ReLU -> hff (r2) (256^2)
  gemm_rot<256, 256, 512, 4, 8, 4, 2><<<dim3(16, 16), 512, 0, stream>>>(
      r1, w1_b, b1, nullptr, r2, 4096, 1024);
  // MLP2 + residual -> out (f32) (128^2, K=4096)
  gemm_rot<128, 128, 256, 2, 4, 4, 1><<<dim3(8, 32), 256, 0, stream>>>(
      r2, w2_b, b2, x2, out, 1024, 4096);
}